// Round 1
// baseline (839.970 us; speedup 1.0000x reference)
//
#include <hip/hip_runtime.h>

#define EPSB 1e-5f
#define B_ 4
#define N_ 256
#define H_ 16
#define D_ 5
#define E_ 4096
#define M_PAIR (B_*N_*N_)   // 262144

// ---- stats slot offsets (floats) in ws ----
enum {
  SO_ANGX = 0,               // ang sum, ang sq, cen sum, cen sq
  SO_CENX = 2,
  SO_ANG2 = 16,  SO_ANG2Q = 32,
  SO_CEN2 = 48,  SO_CEN2Q = 64,
  SO_C1   = 96,  SO_C1Q   = 160,
  SO_C2   = 224, SO_C2Q   = 352,
  SO_C3   = 480, SO_C3Q   = 736,
  SO_FC   = 992, SO_FCQ   = 1008,
  SO_ET1  = 1024, SO_ET1Q = 1040, SO_ET2 = 1056, SO_ET2Q = 1072,
  SO_EL1  = 1088, SO_EL1Q = 1104, SO_EL2 = 1120, SO_EL2Q = 1136,
  SO_EV1  = 1152, SO_EV1Q = 1168, SO_EV2 = 1184, SO_EV2Q = 1200,
  SO_G1   = 1216, SO_G1Q  = 1280,
  SO_G2   = 1344, SO_G2Q  = 1360,
  STATS_FLOATS = 2048
};

// ---- buffer offsets (floats) ----
static constexpr size_t F_Y13  = 2048;                 // y1 (E*64*20) then y3 (E*256*20)
static constexpr size_t F_Y2   = F_Y13 + 20971520;     // E*128*20
static constexpr size_t F_POOL = F_Y2 + 10485760;      // E*256
static constexpr size_t F_FCB  = F_POOL + 1048576;     // E*16 (fc out, later z2 of edgeconv)
static constexpr size_t F_EF   = F_FCB + 65536;        // E*16
static constexpr size_t F_PROJ = F_EF + 65536;         // 1024*16
static constexpr size_t F_Z1EC = F_PROJ + 16384;       // E*64
static constexpr size_t F_EDGEF= F_Z1EC + 262144;      // 4*1025*16

__device__ __forceinline__ float waveSum(float v){
  #pragma unroll
  for(int o=32;o;o>>=1) v += __shfl_down(v,o);
  return v;
}

// block = 256 threads (4 waves). Reduce 16 sums + 16 sumsqs, atomicAdd to ws.
__device__ __forceinline__ void red32_atomic(float* ws, int so, int soq, float* s, float* q){
  __shared__ float red[4][32];
  int tid=threadIdx.x, lane=tid&63, wid=tid>>6;
  #pragma unroll
  for(int k=0;k<16;k++){
    float rs=waveSum(s[k]), rq=waveSum(q[k]);
    if(lane==0){ red[wid][k]=rs; red[wid][16+k]=rq; }
  }
  __syncthreads();
  if(tid<32){
    float t=red[0][tid]+red[1][tid]+red[2][tid]+red[3][tid];
    atomicAdd(&ws[tid<16 ? so+tid : soq+(tid-16)], t);
  }
}

// ---------------- scalar stats of angle & centroid ----------------
__global__ __launch_bounds__(256) void k_scalar_stats(const float* __restrict__ ang,
    const float* __restrict__ cen, float* __restrict__ st){
  int tid = blockIdx.x*256 + threadIdx.x;
  float sa=0, qa=0, sc=0, qc=0;
  for(int i=tid; i<M_PAIR; i += gridDim.x*256){
    float a=ang[i], c=cen[i];
    sa+=a; qa+=a*a; sc+=c; qc+=c*c;
  }
  __shared__ float red[4][4];
  int lane=threadIdx.x&63, wid=threadIdx.x>>6;
  sa=waveSum(sa); qa=waveSum(qa); sc=waveSum(sc); qc=waveSum(qc);
  if(lane==0){ red[wid][0]=sa; red[wid][1]=qa; red[wid][2]=sc; red[wid][3]=qc; }
  __syncthreads();
  if(threadIdx.x<4){
    float t=red[0][threadIdx.x]+red[1][threadIdx.x]+red[2][threadIdx.x]+red[3][threadIdx.x];
    atomicAdd(&st[threadIdx.x], t);
  }
}

// ---------------- layer-2 stats for angle/cent MLPs ----------------
__global__ __launch_bounds__(256) void k_ac_l2stats(const float* __restrict__ x,
    const float* __restrict__ W1, const float* __restrict__ W2,
    float* __restrict__ st, int soX, int soS, int soQ){
  __shared__ float w2s[256];
  __shared__ float Ah[16];
  __shared__ float mu_s, var_s;
  int tid=threadIdx.x;
  w2s[tid]=W2[tid];
  if(tid==0){
    float s=st[soX], qq=st[soX+1];
    float mu=s*(1.0f/262144.0f);
    float v=qq*(1.0f/262144.0f)-mu*mu; if(v<0)v=0;
    mu_s=mu; var_s=v;
  }
  __syncthreads();
  if(tid<16){ float w=W1[tid]; Ah[tid]=w/sqrtf(var_s*w*w+EPSB); }
  __syncthreads();
  float s[16], q[16];
  #pragma unroll
  for(int k=0;k<16;k++){ s[k]=0; q[k]=0; }
  for(int i=blockIdx.x*256+tid; i<M_PAIR; i+=gridDim.x*256){
    float xc=x[i]-mu_s;
    float h1[16];
    #pragma unroll
    for(int h=0;h<16;h++){ float t=xc*Ah[h]; h1[h]=t>0?t:0; }
    #pragma unroll
    for(int k=0;k<16;k++){
      float z=0;
      #pragma unroll
      for(int h=0;h<16;h++) z+=w2s[k*16+h]*h1[h];
      s[k]+=z; q[k]+=z*z;
    }
  }
  red32_atomic(st, soS, soQ, s, q);
}

// ---------------- conv1: [E,12,20] -> y1 [E,64,20] + stats ----------------
__global__ __launch_bounds__(64) void k_conv1(const float* __restrict__ ed,
    const float* __restrict__ w, float* __restrict__ ws){
  __shared__ float wsh[64*36];
  __shared__ float xs[8][12][20];
  int tid=threadIdx.x;
  for(int i=tid;i<64*36;i+=64) wsh[i]=w[i];
  int e0=blockIdx.x*8;
  for(int i=tid;i<8*240;i+=64){
    int e=i/240, r=i%240, l=r/12, c=r%12;
    xs[e][c][l]=ed[(size_t)(e0+e)*240+r];
  }
  __syncthreads();
  int o=tid;
  float* y1=ws+F_Y13;
  float ssum=0, ssq=0;
  for(int e=0;e<8;e++){
    float acc[20];
    #pragma unroll
    for(int l=0;l<20;l++) acc[l]=0;
    for(int c=0;c<12;c++){
      float w0=wsh[o*36+c*3], w1=wsh[o*36+c*3+1], w2=wsh[o*36+c*3+2];
      const float* xr=xs[e][c];
      #pragma unroll
      for(int l=0;l<20;l++){
        float t=w1*xr[l];
        if(l>0)  t+=w0*xr[l-1];
        if(l<19) t+=w2*xr[l+1];
        acc[l]+=t;
      }
    }
    size_t base=((size_t)(e0+e)*64+o)*20;
    #pragma unroll
    for(int l=0;l<20;l++){ y1[base+l]=acc[l]; ssum+=acc[l]; ssq+=acc[l]*acc[l]; }
  }
  atomicAdd(&ws[SO_C1+o], ssum);
  atomicAdd(&ws[SO_C1Q+o], ssq);
}

// ---------------- conv2: bn+lrelu(y1) -> y2 [E,128,20] + stats ----------------
__global__ __launch_bounds__(128) void k_conv2(const float* __restrict__ w, float* __restrict__ ws){
  __shared__ float xs[64][20];
  __shared__ float mI[64][2];
  int tid=threadIdx.x;
  if(tid<64){
    float m=ws[SO_C1+tid]*(1.0f/81920.0f);
    float v=ws[SO_C1Q+tid]*(1.0f/81920.0f)-m*m; if(v<0)v=0;
    mI[tid][0]=m; mI[tid][1]=rsqrtf(v+EPSB);
  }
  __syncthreads();
  int e=blockIdx.x;
  const float* y1=ws+F_Y13+(size_t)e*1280;
  for(int i=tid;i<1280;i+=128){
    int c=i/20;
    float v=(y1[i]-mI[c][0])*mI[c][1];
    xs[c][i%20]= v>=0.f? v : 0.01f*v;
  }
  __syncthreads();
  int o=tid;
  float acc[20];
  #pragma unroll
  for(int l=0;l<20;l++) acc[l]=0;
  const float* wr=w+(size_t)o*192;
  for(int c=0;c<64;c++){
    float w0=wr[c*3], w1=wr[c*3+1], w2=wr[c*3+2];
    const float* xr=xs[c];
    #pragma unroll
    for(int l=0;l<20;l++){
      float t=w1*xr[l];
      if(l>0)  t+=w0*xr[l-1];
      if(l<19) t+=w2*xr[l+1];
      acc[l]+=t;
    }
  }
  float* y2=ws+F_Y2+((size_t)e*128+o)*20;
  float ssum=0, ssq=0;
  #pragma unroll
  for(int l=0;l<20;l++){ y2[l]=acc[l]; ssum+=acc[l]; ssq+=acc[l]*acc[l]; }
  atomicAdd(&ws[SO_C2+o], ssum);
  atomicAdd(&ws[SO_C2Q+o], ssq);
}

// ---------------- conv3: bn+lrelu(y2) -> y3 [E,256,20] + stats ----------------
__global__ __launch_bounds__(256) void k_conv3(const float* __restrict__ w, float* __restrict__ ws){
  __shared__ float xs[128][20];
  __shared__ float mI[128][2];
  int tid=threadIdx.x;
  if(tid<128){
    float m=ws[SO_C2+tid]*(1.0f/81920.0f);
    float v=ws[SO_C2Q+tid]*(1.0f/81920.0f)-m*m; if(v<0)v=0;
    mI[tid][0]=m; mI[tid][1]=rsqrtf(v+EPSB);
  }
  __syncthreads();
  int e=blockIdx.x;
  const float* y2=ws+F_Y2+(size_t)e*2560;
  for(int i=tid;i<2560;i+=256){
    int c=i/20;
    float v=(y2[i]-mI[c][0])*mI[c][1];
    xs[c][i%20]= v>=0.f? v : 0.01f*v;
  }
  __syncthreads();
  int o=tid;
  float acc[20];
  #pragma unroll
  for(int l=0;l<20;l++) acc[l]=0;
  const float* wr=w+(size_t)o*384;
  for(int c=0;c<128;c++){
    float w0=wr[c*3], w1=wr[c*3+1], w2=wr[c*3+2];
    const float* xr=xs[c];
    #pragma unroll
    for(int l=0;l<20;l++){
      float t=w1*xr[l];
      if(l>0)  t+=w0*xr[l-1];
      if(l<19) t+=w2*xr[l+1];
      acc[l]+=t;
    }
  }
  float* y3=ws+F_Y13+((size_t)e*256+o)*20;
  float ssum=0, ssq=0;
  #pragma unroll
  for(int l=0;l<20;l++){ y3[l]=acc[l]; ssum+=acc[l]; ssq+=acc[l]*acc[l]; }
  atomicAdd(&ws[SO_C3+o], ssum);
  atomicAdd(&ws[SO_C3Q+o], ssq);
}

// ---------------- pool: mean_l lrelu(bn(y3)) -> pooled [E,256] ----------------
__global__ __launch_bounds__(256) void k_pool(float* __restrict__ ws){
  int t=blockIdx.x*256+threadIdx.x;   // E*256 threads
  int c=t&255;
  float m=ws[SO_C3+c]*(1.0f/81920.0f);
  float v=ws[SO_C3Q+c]*(1.0f/81920.0f)-m*m; if(v<0)v=0;
  float inv=rsqrtf(v+EPSB);
  const float* y3=ws+F_Y13+(size_t)t*20;
  float s=0;
  #pragma unroll
  for(int l=0;l<20;l++){
    float x=(y3[l]-m)*inv;
    s += x>=0.f? x : 0.01f*x;
  }
  ws[F_POOL+t]=s*(1.0f/20.0f);
}

// ---------------- fc: pooled @ curv_fc.T -> fcb [E,16] + stats ----------------
__global__ __launch_bounds__(256) void k_fc(const float* __restrict__ fcw, float* __restrict__ ws){
  __shared__ float ps[16][260];
  __shared__ float red[4][32];
  int tid=threadIdx.x;
  int e0=blockIdx.x*16;
  for(int i=tid;i<4096;i+=256){
    ps[i>>8][i&255]=ws[F_POOL+(size_t)(e0+(i>>8))*256+(i&255)];
  }
  __syncthreads();
  int e=tid>>4, h=tid&15;
  const float* wr=fcw+(size_t)h*256;
  float z=0;
  for(int c=0;c<256;c++) z+=ps[e][c]*wr[c];
  ws[F_FCB+(size_t)(e0+e)*16+h]=z;
  float s=z, q=z*z;
  #pragma unroll
  for(int o=16;o<64;o<<=1){ s+=__shfl_down(s,o); q+=__shfl_down(q,o); }
  int lane=tid&63, wid=tid>>6;
  if(lane<16){ red[wid][lane]=s; red[wid][16+lane]=q; }
  __syncthreads();
  if(tid<32){
    float v=red[0][tid]+red[1][tid]+red[2][tid]+red[3][tid];
    atomicAdd(&ws[tid<16? SO_FC+tid : SO_FCQ+(tid-16)], v);
  }
}

// ---------------- small-MLP layer-1 stats ----------------
template<int DIM>
__global__ __launch_bounds__(256) void k_small_l1(const float* __restrict__ x,
    const float* __restrict__ W1, float* __restrict__ ws, int so, int soq){
  __shared__ float w1s[16*DIM];
  int tid=threadIdx.x;
  if(tid<16*DIM) w1s[tid]=W1[tid];
  __syncthreads();
  int e=blockIdx.x*256+tid;
  float xv[DIM];
  #pragma unroll
  for(int j=0;j<DIM;j++) xv[j]=x[(size_t)e*DIM+j];
  float s[16], q[16];
  #pragma unroll
  for(int k=0;k<16;k++){
    float z=0;
    #pragma unroll
    for(int j=0;j<DIM;j++) z+=w1s[k*DIM+j]*xv[j];
    s[k]=z; q[k]=z*z;
  }
  red32_atomic(ws, so, soq, s, q);
}

// ---------------- small-MLP layer-2 stats ----------------
template<int DIM>
__global__ __launch_bounds__(256) void k_small_l2(const float* __restrict__ x,
    const float* __restrict__ W1, const float* __restrict__ W2, float* __restrict__ ws,
    int so1, int so1q, int so2, int so2q){
  __shared__ float w1s[16*DIM];
  __shared__ float w2s[256];
  __shared__ float mi[16][2];
  int tid=threadIdx.x;
  if(tid<16*DIM) w1s[tid]=W1[tid];
  w2s[tid]=W2[tid];
  if(tid<16){
    float m=ws[so1+tid]*(1.0f/4096.0f);
    float v=ws[so1q+tid]*(1.0f/4096.0f)-m*m; if(v<0)v=0;
    mi[tid][0]=m; mi[tid][1]=rsqrtf(v+EPSB);
  }
  __syncthreads();
  int e=blockIdx.x*256+tid;
  float xv[DIM];
  #pragma unroll
  for(int j=0;j<DIM;j++) xv[j]=x[(size_t)e*DIM+j];
  float h1[16];
  #pragma unroll
  for(int h=0;h<16;h++){
    float z=0;
    #pragma unroll
    for(int j=0;j<DIM;j++) z+=w1s[h*DIM+j]*xv[j];
    z=(z-mi[h][0])*mi[h][1];
    h1[h]=z>0?z:0;
  }
  float s[16], q[16];
  #pragma unroll
  for(int k=0;k<16;k++){
    float z=0;
    #pragma unroll
    for(int h=0;h<16;h++) z+=w2s[k*16+h]*h1[h];
    s[k]=z; q[k]=z*z;
  }
  red32_atomic(ws, so2, so2q, s, q);
}

// ---------------- ef assembly: fc-bn + 3 small MLPs -> ef [E,16] ----------------
__device__ __constant__ int EF_BASES[7][2] = {
  {SO_ET1,SO_ET1Q},{SO_ET2,SO_ET2Q},{SO_EL1,SO_EL1Q},{SO_EL2,SO_EL2Q},
  {SO_EV1,SO_EV1Q},{SO_EV2,SO_EV2Q},{SO_FC,SO_FCQ}
};

__global__ __launch_bounds__(256) void k_ef(
    const float* __restrict__ et, const float* __restrict__ etW1, const float* __restrict__ etW2,
    const float* __restrict__ el, const float* __restrict__ elW1, const float* __restrict__ elW2,
    const float* __restrict__ ev, const float* __restrict__ evW1, const float* __restrict__ evW2,
    float* __restrict__ ws){
  __shared__ float w1et[176], w1el[16], w1ev[48];
  __shared__ float w2et[256], w2el[256], w2ev[256];
  __shared__ float mi[7][16][2];
  int tid=threadIdx.x;
  if(tid<176) w1et[tid]=etW1[tid];
  if(tid<16)  w1el[tid]=elW1[tid];
  if(tid<48)  w1ev[tid]=evW1[tid];
  w2et[tid]=etW2[tid]; w2el[tid]=elW2[tid]; w2ev[tid]=evW2[tid];
  if(tid<112){
    int g=tid>>4, h=tid&15;
    float m=ws[EF_BASES[g][0]+h]*(1.0f/4096.0f);
    float v=ws[EF_BASES[g][1]+h]*(1.0f/4096.0f)-m*m; if(v<0)v=0;
    mi[g][h][0]=m; mi[g][h][1]=rsqrtf(v+EPSB);
  }
  __syncthreads();
  int e=blockIdx.x*256+tid;
  float acc[16];
  #pragma unroll
  for(int h=0;h<16;h++){
    float z=ws[F_FCB+(size_t)e*16+h];
    acc[h]=(z-mi[6][h][0])*mi[6][h][1];   // fc: BN, no relu
  }
  { // etype (dim 11)
    float xv[11];
    #pragma unroll
    for(int j=0;j<11;j++) xv[j]=et[(size_t)e*11+j];
    float h1[16];
    #pragma unroll
    for(int h=0;h<16;h++){
      float z=0;
      #pragma unroll
      for(int j=0;j<11;j++) z+=w1et[h*11+j]*xv[j];
      z=(z-mi[0][h][0])*mi[0][h][1];
      h1[h]=z>0?z:0;
    }
    #pragma unroll
    for(int k=0;k<16;k++){
      float z=0;
      #pragma unroll
      for(int h=0;h<16;h++) z+=w2et[k*16+h]*h1[h];
      z=(z-mi[1][k][0])*mi[1][k][1];
      acc[k]+= z>0?z:0;
    }
  }
  { // elen (dim 1)
    float x=el[e];
    float h1[16];
    #pragma unroll
    for(int h=0;h<16;h++){
      float z=x*w1el[h];
      z=(z-mi[2][h][0])*mi[2][h][1];
      h1[h]=z>0?z:0;
    }
    #pragma unroll
    for(int k=0;k<16;k++){
      float z=0;
      #pragma unroll
      for(int h=0;h<16;h++) z+=w2el[k*16+h]*h1[h];
      z=(z-mi[3][k][0])*mi[3][k][1];
      acc[k]+= z>0?z:0;
    }
  }
  { // econv (dim 3)
    float xv[3];
    #pragma unroll
    for(int j=0;j<3;j++) xv[j]=ev[(size_t)e*3+j];
    float h1[16];
    #pragma unroll
    for(int h=0;h<16;h++){
      float z=0;
      #pragma unroll
      for(int j=0;j<3;j++) z+=w1ev[h*3+j]*xv[j];
      z=(z-mi[4][h][0])*mi[4][h][1];
      h1[h]=z>0?z:0;
    }
    #pragma unroll
    for(int k=0;k<16;k++){
      float z=0;
      #pragma unroll
      for(int h=0;h<16;h++) z+=w2ev[k*16+h]*h1[h];
      z=(z-mi[5][k][0])*mi[5][k][1];
      acc[k]+= z>0?z:0;
    }
  }
  #pragma unroll
  for(int h=0;h<16;h++) ws[F_EF+(size_t)e*16+h]=acc[h];
}

// ---------------- proj: node_feat @ ec_Wp.T -> proj [1024,16] ----------------
__global__ __launch_bounds__(256) void k_proj(const float* __restrict__ nf,
    const float* __restrict__ Wp, float* __restrict__ ws){
  __shared__ float wps[4096];
  int tid=threadIdx.x;
  for(int i=tid;i<4096;i+=256) wps[i]=Wp[i];
  __syncthreads();
  int t=blockIdx.x*256+tid;
  int v=t>>4, h=t&15;
  const float* row=nf+(size_t)v*256;
  const float* wr=wps+h*256;
  float z=0;
  for(int c=0;c<256;c++) z+=row[c]*wr[c];
  ws[F_PROJ+t]=z;
}

// ---------------- agg + edgeconv layer1 -> z1ec [E,64] + stats ----------------
__global__ __launch_bounds__(256) void k_agg(const int* __restrict__ src, const int* __restrict__ dst,
    const float* __restrict__ ecW1, float* __restrict__ ws){
  __shared__ float w1s[1024];
  int tid=threadIdx.x;
  for(int i=tid;i<1024;i+=256) w1s[i]=ecW1[i];
  __syncthreads();
  int e=blockIdx.x*256+tid;
  int s=src[e], d=dst[e];
  float a[16];
  #pragma unroll
  for(int h=0;h<16;h++)
    a[h]=ws[F_EF+(size_t)e*16+h]+ws[F_PROJ+(size_t)s*16+h]+ws[F_PROJ+(size_t)d*16+h];
  int lane=tid&63;
  for(int o=0;o<64;o++){
    float z=0;
    #pragma unroll
    for(int h=0;h<16;h++) z+=w1s[o*16+h]*a[h];
    ws[F_Z1EC+(size_t)e*64+o]=z;
    float rs=waveSum(z), rq=waveSum(z*z);
    if(lane==0){ atomicAdd(&ws[SO_G1+o],rs); atomicAdd(&ws[SO_G1Q+o],rq); }
  }
}

// ---------------- edgeconv layer2 -> z2 [E,16] (in F_FCB) + stats ----------------
__global__ __launch_bounds__(256) void k_ec2(const float* __restrict__ ecW2, float* __restrict__ ws){
  __shared__ float w2s[1024];
  __shared__ float mi[64][2];
  int tid=threadIdx.x;
  for(int i=tid;i<1024;i+=256) w2s[i]=ecW2[i];
  if(tid<64){
    float m=ws[SO_G1+tid]*(1.0f/4096.0f);
    float v=ws[SO_G1Q+tid]*(1.0f/4096.0f)-m*m; if(v<0)v=0;
    mi[tid][0]=m; mi[tid][1]=rsqrtf(v+EPSB);
  }
  __syncthreads();
  int e=blockIdx.x*256+tid;
  float acc[16];
  #pragma unroll
  for(int k=0;k<16;k++) acc[k]=0;
  for(int o=0;o<64;o++){
    float z=ws[F_Z1EC+(size_t)e*64+o];
    float h=(z-mi[o][0])*mi[o][1];
    h=h>0?h:0;
    #pragma unroll
    for(int k=0;k<16;k++) acc[k]+=w2s[k*64+o]*h;
  }
  float s[16], q[16];
  #pragma unroll
  for(int k=0;k<16;k++){
    ws[F_FCB+(size_t)e*16+k]=acc[k];
    s[k]=acc[k]; q[k]=acc[k]*acc[k];
  }
  red32_atomic(ws, SO_G2, SO_G2Q, s, q);
}

// ---------------- edge_feature fill [4,1025,16] ----------------
__global__ __launch_bounds__(256) void k_ef2(float* __restrict__ ws){
  int t=blockIdx.x*256+threadIdx.x;
  if(t>=4*1025*16) return;
  int h=t&15, r=t>>4;
  int b=r/1025, pos=r%1025;
  float v=0;
  if(pos<1024){
    int e=b*1024+pos;
    float z=ws[F_FCB+(size_t)e*16+h];
    float m=ws[SO_G2+h]*(1.0f/4096.0f);
    float va=ws[SO_G2Q+h]*(1.0f/4096.0f)-m*m; if(va<0)va=0;
    v=(z-m)*rsqrtf(va+EPSB);
    v=v>0?v:0;
  }
  ws[F_EDGEF+t]=v;
}

// ---------------- main per-pair kernel: interior output ----------------
__global__ __launch_bounds__(256) void k_pair(const float* __restrict__ ab,
    const int* __restrict__ sd, const float* __restrict__ ang, const float* __restrict__ cen,
    const int* __restrict__ ep, const float* __restrict__ sdemb, const float* __restrict__ edisw,
    const float* __restrict__ angW1, const float* __restrict__ angW2,
    const float* __restrict__ cenW1, const float* __restrict__ cenW2,
    const float* __restrict__ ws, float* __restrict__ out){
  __shared__ float wd[1280];
  __shared__ float w2a[256], w2c[256];
  __shared__ float Aa[16], Ac[16], m2a[16], i2a[16], m2c[16], i2c[16];
  __shared__ float muA, muC, varA, varC;
  int tid=threadIdx.x;
  for(int i=tid;i<1280;i+=256) wd[i]=edisw[i];
  w2a[tid]=angW2[tid]; w2c[tid]=cenW2[tid];
  if(tid==0){
    float s=ws[SO_ANGX], q=ws[SO_ANGX+1];
    float mu=s*(1.0f/262144.0f);
    float v=q*(1.0f/262144.0f)-mu*mu; if(v<0)v=0;
    muA=mu; varA=v;
    s=ws[SO_CENX]; q=ws[SO_CENX+1];
    mu=s*(1.0f/262144.0f);
    v=q*(1.0f/262144.0f)-mu*mu; if(v<0)v=0;
    muC=mu; varC=v;
  }
  __syncthreads();
  if(tid<16){
    float w=angW1[tid]; Aa[tid]=w/sqrtf(varA*w*w+EPSB);
    float m=ws[SO_ANG2+tid]*(1.0f/262144.0f);
    float v=ws[SO_ANG2Q+tid]*(1.0f/262144.0f)-m*m; if(v<0)v=0;
    m2a[tid]=m; i2a[tid]=rsqrtf(v+EPSB);
  } else if(tid<32){
    int h=tid-16;
    float w=cenW1[h]; Ac[h]=w/sqrtf(varC*w*w+EPSB);
    float m=ws[SO_CEN2+h]*(1.0f/262144.0f);
    float v=ws[SO_CEN2Q+h]*(1.0f/262144.0f)-m*m; if(v<0)v=0;
    m2c[h]=m; i2c[h]=rsqrtf(v+EPSB);
  }
  __syncthreads();
  int t=blockIdx.x*256+tid;            // b,i,j
  int b=t>>16, rem=t&65535, i=rem>>8, j=rem&255;
  int sdv=sd[t];
  float xa=ang[t], xc0=cen[t];
  float acc[16];
  const float* se=sdemb+(size_t)sdv*16;
  #pragma unroll
  for(int k=0;k<16;k++) acc[k]=se[k];
  { // angle MLP
    float xc=xa-muA;
    float h1[16];
    #pragma unroll
    for(int h=0;h<16;h++){ float v=xc*Aa[h]; h1[h]=v>0?v:0; }
    #pragma unroll
    for(int k=0;k<16;k++){
      float z=0;
      #pragma unroll
      for(int h=0;h<16;h++) z+=w2a[k*16+h]*h1[h];
      float r=(z-m2a[k])*i2a[k];
      acc[k]+= r>0?r:0;
    }
  }
  { // centroid MLP
    float xc=xc0-muC;
    float h1[16];
    #pragma unroll
    for(int h=0;h<16;h++){ float v=xc*Ac[h]; h1[h]=v>0?v:0; }
    #pragma unroll
    for(int k=0;k<16;k++){
      float z=0;
      #pragma unroll
      for(int h=0;h<16;h++) z+=w2c[k*16+h]*h1[h];
      float r=(z-m2c[k])*i2c[k];
      acc[k]+= r>0?r:0;
    }
  }
  { // multi-hop edge bias
    int sdm = sdv==0 ? 1 : sdv;
    if(sdm>1) sdm-=1;
    if(sdm>5) sdm=5;
    float inv=1.0f/((float)sdm+1e-6f);
    float eb[16];
    #pragma unroll
    for(int k=0;k<16;k++) eb[k]=0;
    const float* EF=ws+F_EDGEF+(size_t)b*1025*16;
    #pragma unroll
    for(int d=0;d<5;d++){
      int idx=ep[(size_t)t*5+d];
      const float* r=EF+(size_t)idx*16;
      float e16[16];
      #pragma unroll
      for(int k=0;k<16;k+=4){
        float4 v=*(const float4*)(r+k);
        e16[k]=v.x; e16[k+1]=v.y; e16[k+2]=v.z; e16[k+3]=v.w;
      }
      const float* wdd=wd+d*256;
      #pragma unroll
      for(int h=0;h<16;h++){
        float evv=e16[h];
        #pragma unroll
        for(int k=0;k<16;k++) eb[k]+=evv*wdd[h*16+k];
      }
    }
    #pragma unroll
    for(int k=0;k<16;k++) acc[k]+=eb[k]*inv;
  }
  float base2=2.0f*ab[(size_t)b*66049+(size_t)(i+1)*257+(j+1)];
  #pragma unroll
  for(int k=0;k<16;k++)
    out[(((size_t)b*16+k)*257+(i+1))*257+(j+1)]=acc[k]+base2;
}

// ---------------- borders: row 0 and col 0 ----------------
__global__ __launch_bounds__(256) void k_border(const float* __restrict__ ab,
    const float* __restrict__ virt, float* __restrict__ out){
  int t=blockIdx.x*256+threadIdx.x;
  if(t>=4*16*513) return;
  int idx=t%513, bh=t/513;
  int b=bh>>4, h=bh&15;
  float v=virt[h];
  if(idx<257){
    out[(((size_t)b*16+h)*257)*257+idx]=2.0f*ab[(size_t)b*66049+idx]+v;
  } else {
    int p=idx-256;   // 1..256
    out[(((size_t)b*16+h)*257+p)*257]=2.0f*ab[(size_t)b*66049+(size_t)p*257]+v;
  }
}

extern "C" void kernel_launch(void* const* d_in, const int* in_sizes, int n_in,
                              void* d_out, int out_size, void* d_ws, size_t ws_size,
                              hipStream_t stream) {
  const float* ab    =(const float*)d_in[0];
  const int*   sdist =(const int*)  d_in[1];
  const float* ang   =(const float*)d_in[2];
  const float* cen   =(const float*)d_in[3];
  const int*   ep    =(const int*)  d_in[4];
  const float* edata =(const float*)d_in[5];
  const float* etype =(const float*)d_in[6];
  const float* elen  =(const float*)d_in[7];
  const float* econv =(const float*)d_in[8];
  const int*   src   =(const int*)  d_in[10];
  const int*   dst   =(const int*)  d_in[11];
  const float* nf    =(const float*)d_in[12];
  const float* sdemb =(const float*)d_in[13];
  const float* virt  =(const float*)d_in[14];
  const float* angW1 =(const float*)d_in[15];
  const float* angW2 =(const float*)d_in[16];
  const float* cenW1 =(const float*)d_in[17];
  const float* cenW2 =(const float*)d_in[18];
  const float* etW1  =(const float*)d_in[19];
  const float* etW2  =(const float*)d_in[20];
  const float* elW1  =(const float*)d_in[21];
  const float* elW2  =(const float*)d_in[22];
  const float* evW1  =(const float*)d_in[23];
  const float* evW2  =(const float*)d_in[24];
  const float* c1w   =(const float*)d_in[25];
  const float* c2w   =(const float*)d_in[26];
  const float* c3w   =(const float*)d_in[27];
  const float* fcw   =(const float*)d_in[28];
  const float* edisw =(const float*)d_in[29];
  const float* ecWp  =(const float*)d_in[30];
  const float* ecW1  =(const float*)d_in[31];
  const float* ecW2  =(const float*)d_in[32];
  float* ws=(float*)d_ws;
  float* out=(float*)d_out;

  hipMemsetAsync(d_ws, 0, STATS_FLOATS*sizeof(float), stream);

  k_scalar_stats<<<256,256,0,stream>>>(ang,cen,ws);
  k_ac_l2stats<<<128,256,0,stream>>>(ang,angW1,angW2,ws,SO_ANGX,SO_ANG2,SO_ANG2Q);
  k_ac_l2stats<<<128,256,0,stream>>>(cen,cenW1,cenW2,ws,SO_CENX,SO_CEN2,SO_CEN2Q);

  k_conv1<<<512,64,0,stream>>>(edata,c1w,ws);
  k_conv2<<<4096,128,0,stream>>>(c2w,ws);
  k_conv3<<<4096,256,0,stream>>>(c3w,ws);
  k_pool<<<4096,256,0,stream>>>(ws);
  k_fc<<<256,256,0,stream>>>(fcw,ws);

  k_small_l1<11><<<16,256,0,stream>>>(etype,etW1,ws,SO_ET1,SO_ET1Q);
  k_small_l1<1> <<<16,256,0,stream>>>(elen ,elW1,ws,SO_EL1,SO_EL1Q);
  k_small_l1<3> <<<16,256,0,stream>>>(econv,evW1,ws,SO_EV1,SO_EV1Q);
  k_small_l2<11><<<16,256,0,stream>>>(etype,etW1,etW2,ws,SO_ET1,SO_ET1Q,SO_ET2,SO_ET2Q);
  k_small_l2<1> <<<16,256,0,stream>>>(elen ,elW1,elW2,ws,SO_EL1,SO_EL1Q,SO_EL2,SO_EL2Q);
  k_small_l2<3> <<<16,256,0,stream>>>(econv,evW1,evW2,ws,SO_EV1,SO_EV1Q,SO_EV2,SO_EV2Q);

  k_ef<<<16,256,0,stream>>>(etype,etW1,etW2,elen,elW1,elW2,econv,evW1,evW2,ws);
  k_proj<<<64,256,0,stream>>>(nf,ecWp,ws);
  k_agg<<<16,256,0,stream>>>(src,dst,ecW1,ws);
  k_ec2<<<16,256,0,stream>>>(ecW2,ws);
  k_ef2<<<257,256,0,stream>>>(ws);

  k_pair<<<1024,256,0,stream>>>(ab,sdist,ang,cen,ep,sdemb,edisw,angW1,angW2,cenW1,cenW2,ws,out);
  k_border<<<129,256,0,stream>>>(ab,virt,out);
}

// Round 2
// 716.209 us; speedup vs baseline: 1.1728x; 1.1728x over previous
//
#include <hip/hip_runtime.h>

#define EPSB 1e-5f
#define B_ 4
#define N_ 256
#define H_ 16
#define D_ 5
#define E_ 4096
#define M_PAIR (B_*N_*N_)   // 262144

// ---- stats slot offsets (floats) in ws ----
enum {
  SO_ANGX = 0,               // ang sum, ang sq, cen sum, cen sq
  SO_CENX = 2,
  SO_ANG2 = 16,  SO_ANG2Q = 32,
  SO_CEN2 = 48,  SO_CEN2Q = 64,
  SO_C1   = 96,  SO_C1Q   = 160,
  SO_C2   = 224, SO_C2Q   = 352,
  SO_C3   = 480, SO_C3Q   = 736,
  SO_FC   = 992, SO_FCQ   = 1008,
  SO_ET1  = 1024, SO_ET1Q = 1040, SO_ET2 = 1056, SO_ET2Q = 1072,
  SO_EL1  = 1088, SO_EL1Q = 1104, SO_EL2 = 1120, SO_EL2Q = 1136,
  SO_EV1  = 1152, SO_EV1Q = 1168, SO_EV2 = 1184, SO_EV2Q = 1200,
  SO_G1   = 1216, SO_G1Q  = 1280,
  SO_G2   = 1344, SO_G2Q  = 1360,
  STATS_FLOATS = 2048
};

// ---- buffer offsets (floats) ----
static constexpr size_t F_Y13  = 2048;                 // y1 (E*64*20) then y3 (E*256*20)
static constexpr size_t F_Y2   = F_Y13 + 20971520;     // E*128*20
static constexpr size_t F_POOL = F_Y2 + 10485760;      // E*256
static constexpr size_t F_FCB  = F_POOL + 1048576;     // E*16 (fc out, later z2 of edgeconv)
static constexpr size_t F_EF   = F_FCB + 65536;        // E*16
static constexpr size_t F_PROJ = F_EF + 65536;         // 1024*16
static constexpr size_t F_Z1EC = F_PROJ + 16384;       // E*64
static constexpr size_t F_EDGEF= F_Z1EC + 262144;      // 4*1025*16

__device__ __forceinline__ float waveSum(float v){
  #pragma unroll
  for(int o=32;o;o>>=1) v += __shfl_down(v,o);
  return v;
}

// block = 256 threads (4 waves). Reduce 16 sums + 16 sumsqs, atomicAdd to ws.
__device__ __forceinline__ void red32_atomic(float* ws, int so, int soq, float* s, float* q){
  __shared__ float red[4][32];
  int tid=threadIdx.x, lane=tid&63, wid=tid>>6;
  #pragma unroll
  for(int k=0;k<16;k++){
    float rs=waveSum(s[k]), rq=waveSum(q[k]);
    if(lane==0){ red[wid][k]=rs; red[wid][16+k]=rq; }
  }
  __syncthreads();
  if(tid<32){
    float t=red[0][tid]+red[1][tid]+red[2][tid]+red[3][tid];
    atomicAdd(&ws[tid<16 ? so+tid : soq+(tid-16)], t);
  }
}

// ---------------- scalar stats of angle & centroid ----------------
__global__ __launch_bounds__(256) void k_scalar_stats(const float* __restrict__ ang,
    const float* __restrict__ cen, float* __restrict__ st){
  int tid = blockIdx.x*256 + threadIdx.x;
  float sa=0, qa=0, sc=0, qc=0;
  for(int i=tid; i<M_PAIR; i += gridDim.x*256){
    float a=ang[i], c=cen[i];
    sa+=a; qa+=a*a; sc+=c; qc+=c*c;
  }
  __shared__ float red[4][4];
  int lane=threadIdx.x&63, wid=threadIdx.x>>6;
  sa=waveSum(sa); qa=waveSum(qa); sc=waveSum(sc); qc=waveSum(qc);
  if(lane==0){ red[wid][0]=sa; red[wid][1]=qa; red[wid][2]=sc; red[wid][3]=qc; }
  __syncthreads();
  if(threadIdx.x<4){
    float t=red[0][threadIdx.x]+red[1][threadIdx.x]+red[2][threadIdx.x]+red[3][threadIdx.x];
    atomicAdd(&st[threadIdx.x], t);
  }
}

// ---------------- layer-2 stats for angle/cent MLPs ----------------
__global__ __launch_bounds__(256) void k_ac_l2stats(const float* __restrict__ x,
    const float* __restrict__ W1, const float* __restrict__ W2,
    float* __restrict__ st, int soX, int soS, int soQ){
  __shared__ float w2s[256];
  __shared__ float Ah[16];
  __shared__ float mu_s, var_s;
  int tid=threadIdx.x;
  w2s[tid]=W2[tid];
  if(tid==0){
    float s=st[soX], qq=st[soX+1];
    float mu=s*(1.0f/262144.0f);
    float v=qq*(1.0f/262144.0f)-mu*mu; if(v<0)v=0;
    mu_s=mu; var_s=v;
  }
  __syncthreads();
  if(tid<16){ float w=W1[tid]; Ah[tid]=w/sqrtf(var_s*w*w+EPSB); }
  __syncthreads();
  float s[16], q[16];
  #pragma unroll
  for(int k=0;k<16;k++){ s[k]=0; q[k]=0; }
  for(int i=blockIdx.x*256+tid; i<M_PAIR; i+=gridDim.x*256){
    float xc=x[i]-mu_s;
    float h1[16];
    #pragma unroll
    for(int h=0;h<16;h++){ float t=xc*Ah[h]; h1[h]=t>0?t:0; }
    #pragma unroll
    for(int k=0;k<16;k++){
      float z=0;
      #pragma unroll
      for(int h=0;h<16;h++) z+=w2s[k*16+h]*h1[h];
      s[k]+=z; q[k]+=z*z;
    }
  }
  red32_atomic(st, soS, soQ, s, q);
}

// ---------------- conv1: [E,12,20] -> y1 [E,64,20] + stats ----------------
__global__ __launch_bounds__(64) void k_conv1(const float* __restrict__ ed,
    const float* __restrict__ w, float* __restrict__ ws){
  __shared__ float wsh[64*36];
  __shared__ float xs[8][12][20];
  int tid=threadIdx.x;
  for(int i=tid;i<64*36;i+=64) wsh[i]=w[i];
  int e0=blockIdx.x*8;
  for(int i=tid;i<8*240;i+=64){
    int e=i/240, r=i%240, l=r/12, c=r%12;
    xs[e][c][l]=ed[(size_t)(e0+e)*240+r];
  }
  __syncthreads();
  int o=tid;
  float* y1=ws+F_Y13;
  float ssum=0, ssq=0;
  for(int e=0;e<8;e++){
    float acc[20];
    #pragma unroll
    for(int l=0;l<20;l++) acc[l]=0;
    for(int c=0;c<12;c++){
      float w0=wsh[o*36+c*3], w1=wsh[o*36+c*3+1], w2=wsh[o*36+c*3+2];
      const float* xr=xs[e][c];
      #pragma unroll
      for(int l=0;l<20;l++){
        float t=w1*xr[l];
        if(l>0)  t+=w0*xr[l-1];
        if(l<19) t+=w2*xr[l+1];
        acc[l]+=t;
      }
    }
    size_t base=((size_t)(e0+e)*64+o)*20;
    #pragma unroll
    for(int l=0;l<20;l++){ y1[base+l]=acc[l]; ssum+=acc[l]; ssq+=acc[l]*acc[l]; }
  }
  atomicAdd(&ws[SO_C1+o], ssum);
  atomicAdd(&ws[SO_C1Q+o], ssq);
}

// ---------------- conv2: bn+lrelu(y1) -> y2 [E,128,20] + stats ----------------
// block = 128 threads (thread = output channel o), 2 edges per block.
__global__ __launch_bounds__(128) void k_conv2(const float* __restrict__ w, float* __restrict__ ws){
  __shared__ float xs[2][64][20];
  __shared__ float mI[64][2];
  int tid=threadIdx.x;
  if(tid<64){
    float m=ws[SO_C1+tid]*(1.0f/81920.0f);
    float v=ws[SO_C1Q+tid]*(1.0f/81920.0f)-m*m; if(v<0)v=0;
    mI[tid][0]=m; mI[tid][1]=rsqrtf(v+EPSB);
  }
  __syncthreads();
  int e0=blockIdx.x*2;
  const float* y1=ws+F_Y13+(size_t)e0*1280;
  for(int i=tid;i<2560;i+=128){
    int e=i/1280, r=i%1280, c=r/20;
    float v=(y1[i]-mI[c][0])*mI[c][1];
    xs[e][c][r%20]= v>=0.f? v : 0.01f*v;
  }
  __syncthreads();
  int o=tid;
  float acc0[20], acc1[20];
  #pragma unroll
  for(int l=0;l<20;l++){ acc0[l]=0; acc1[l]=0; }
  const float* wr=w+(size_t)o*192;
  for(int c4=0;c4<16;c4++){
    float4 wa=*(const float4*)(wr+c4*12);
    float4 wb=*(const float4*)(wr+c4*12+4);
    float4 wc=*(const float4*)(wr+c4*12+8);
    float wf[12]={wa.x,wa.y,wa.z,wa.w,wb.x,wb.y,wb.z,wb.w,wc.x,wc.y,wc.z,wc.w};
    #pragma unroll
    for(int i=0;i<4;i++){
      int c=c4*4+i;
      float w0=wf[i*3], w1=wf[i*3+1], w2=wf[i*3+2];
      {
        const float* xr=xs[0][c];
        float x[20];
        #pragma unroll
        for(int q=0;q<5;q++){ float4 v=*(const float4*)(xr+q*4);
          x[q*4]=v.x; x[q*4+1]=v.y; x[q*4+2]=v.z; x[q*4+3]=v.w; }
        #pragma unroll
        for(int l=0;l<20;l++){
          float t=w1*x[l];
          if(l>0)  t+=w0*x[l-1];
          if(l<19) t+=w2*x[l+1];
          acc0[l]+=t;
        }
      }
      {
        const float* xr=xs[1][c];
        float x[20];
        #pragma unroll
        for(int q=0;q<5;q++){ float4 v=*(const float4*)(xr+q*4);
          x[q*4]=v.x; x[q*4+1]=v.y; x[q*4+2]=v.z; x[q*4+3]=v.w; }
        #pragma unroll
        for(int l=0;l<20;l++){
          float t=w1*x[l];
          if(l>0)  t+=w0*x[l-1];
          if(l<19) t+=w2*x[l+1];
          acc1[l]+=t;
        }
      }
    }
  }
  float ssum=0, ssq=0;
  float* y2a=ws+F_Y2+((size_t)e0*128+o)*20;
  float* y2b=ws+F_Y2+((size_t)(e0+1)*128+o)*20;
  #pragma unroll
  for(int q=0;q<5;q++){
    *(float4*)(y2a+q*4)=make_float4(acc0[q*4],acc0[q*4+1],acc0[q*4+2],acc0[q*4+3]);
    *(float4*)(y2b+q*4)=make_float4(acc1[q*4],acc1[q*4+1],acc1[q*4+2],acc1[q*4+3]);
  }
  #pragma unroll
  for(int l=0;l<20;l++){
    ssum+=acc0[l]+acc1[l];
    ssq +=acc0[l]*acc0[l]+acc1[l]*acc1[l];
  }
  atomicAdd(&ws[SO_C2+o], ssum);
  atomicAdd(&ws[SO_C2Q+o], ssq);
}

// ---------------- conv3: bn+lrelu(y2) -> y3 [E,256,20] + stats ----------------
// block = 256 threads (thread = output channel o), 2 edges per block.
__global__ __launch_bounds__(256) void k_conv3(const float* __restrict__ w, float* __restrict__ ws){
  __shared__ float xs[2][128][20];
  __shared__ float mI[128][2];
  int tid=threadIdx.x;
  if(tid<128){
    float m=ws[SO_C2+tid]*(1.0f/81920.0f);
    float v=ws[SO_C2Q+tid]*(1.0f/81920.0f)-m*m; if(v<0)v=0;
    mI[tid][0]=m; mI[tid][1]=rsqrtf(v+EPSB);
  }
  __syncthreads();
  int e0=blockIdx.x*2;
  const float* y2=ws+F_Y2+(size_t)e0*2560;
  for(int i=tid;i<5120;i+=256){
    int e=i/2560, r=i%2560, c=r/20;
    float v=(y2[i]-mI[c][0])*mI[c][1];
    xs[e][c][r%20]= v>=0.f? v : 0.01f*v;
  }
  __syncthreads();
  int o=tid;
  float acc0[20], acc1[20];
  #pragma unroll
  for(int l=0;l<20;l++){ acc0[l]=0; acc1[l]=0; }
  const float* wr=w+(size_t)o*384;
  for(int c4=0;c4<32;c4++){
    float4 wa=*(const float4*)(wr+c4*12);
    float4 wb=*(const float4*)(wr+c4*12+4);
    float4 wc=*(const float4*)(wr+c4*12+8);
    float wf[12]={wa.x,wa.y,wa.z,wa.w,wb.x,wb.y,wb.z,wb.w,wc.x,wc.y,wc.z,wc.w};
    #pragma unroll
    for(int i=0;i<4;i++){
      int c=c4*4+i;
      float w0=wf[i*3], w1=wf[i*3+1], w2=wf[i*3+2];
      {
        const float* xr=xs[0][c];
        float x[20];
        #pragma unroll
        for(int q=0;q<5;q++){ float4 v=*(const float4*)(xr+q*4);
          x[q*4]=v.x; x[q*4+1]=v.y; x[q*4+2]=v.z; x[q*4+3]=v.w; }
        #pragma unroll
        for(int l=0;l<20;l++){
          float t=w1*x[l];
          if(l>0)  t+=w0*x[l-1];
          if(l<19) t+=w2*x[l+1];
          acc0[l]+=t;
        }
      }
      {
        const float* xr=xs[1][c];
        float x[20];
        #pragma unroll
        for(int q=0;q<5;q++){ float4 v=*(const float4*)(xr+q*4);
          x[q*4]=v.x; x[q*4+1]=v.y; x[q*4+2]=v.z; x[q*4+3]=v.w; }
        #pragma unroll
        for(int l=0;l<20;l++){
          float t=w1*x[l];
          if(l>0)  t+=w0*x[l-1];
          if(l<19) t+=w2*x[l+1];
          acc1[l]+=t;
        }
      }
    }
  }
  float ssum=0, ssq=0;
  float* y3a=ws+F_Y13+((size_t)e0*256+o)*20;
  float* y3b=ws+F_Y13+((size_t)(e0+1)*256+o)*20;
  #pragma unroll
  for(int q=0;q<5;q++){
    *(float4*)(y3a+q*4)=make_float4(acc0[q*4],acc0[q*4+1],acc0[q*4+2],acc0[q*4+3]);
    *(float4*)(y3b+q*4)=make_float4(acc1[q*4],acc1[q*4+1],acc1[q*4+2],acc1[q*4+3]);
  }
  #pragma unroll
  for(int l=0;l<20;l++){
    ssum+=acc0[l]+acc1[l];
    ssq +=acc0[l]*acc0[l]+acc1[l]*acc1[l];
  }
  atomicAdd(&ws[SO_C3+o], ssum);
  atomicAdd(&ws[SO_C3Q+o], ssq);
}

// ---------------- pool: mean_l lrelu(bn(y3)) -> pooled [E,256] ----------------
__global__ __launch_bounds__(256) void k_pool(float* __restrict__ ws){
  int t=blockIdx.x*256+threadIdx.x;   // E*256 threads
  int c=t&255;
  float m=ws[SO_C3+c]*(1.0f/81920.0f);
  float v=ws[SO_C3Q+c]*(1.0f/81920.0f)-m*m; if(v<0)v=0;
  float inv=rsqrtf(v+EPSB);
  const float* y3=ws+F_Y13+(size_t)t*20;
  float s=0;
  #pragma unroll
  for(int l=0;l<20;l++){
    float x=(y3[l]-m)*inv;
    s += x>=0.f? x : 0.01f*x;
  }
  ws[F_POOL+t]=s*(1.0f/20.0f);
}

// ---------------- fc: pooled @ curv_fc.T -> fcb [E,16] + stats ----------------
__global__ __launch_bounds__(256) void k_fc(const float* __restrict__ fcw, float* __restrict__ ws){
  __shared__ float ps[16][260];
  __shared__ float red[4][32];
  int tid=threadIdx.x;
  int e0=blockIdx.x*16;
  for(int i=tid;i<4096;i+=256){
    ps[i>>8][i&255]=ws[F_POOL+(size_t)(e0+(i>>8))*256+(i&255)];
  }
  __syncthreads();
  int e=tid>>4, h=tid&15;
  const float* wr=fcw+(size_t)h*256;
  float z=0;
  for(int c=0;c<256;c++) z+=ps[e][c]*wr[c];
  ws[F_FCB+(size_t)(e0+e)*16+h]=z;
  float s=z, q=z*z;
  #pragma unroll
  for(int o=16;o<64;o<<=1){ s+=__shfl_down(s,o); q+=__shfl_down(q,o); }
  int lane=tid&63, wid=tid>>6;
  if(lane<16){ red[wid][lane]=s; red[wid][16+lane]=q; }
  __syncthreads();
  if(tid<32){
    float v=red[0][tid]+red[1][tid]+red[2][tid]+red[3][tid];
    atomicAdd(&ws[tid<16? SO_FC+tid : SO_FCQ+(tid-16)], v);
  }
}

// ---------------- small-MLP layer-1 stats ----------------
template<int DIM>
__global__ __launch_bounds__(256) void k_small_l1(const float* __restrict__ x,
    const float* __restrict__ W1, float* __restrict__ ws, int so, int soq){
  __shared__ float w1s[16*DIM];
  int tid=threadIdx.x;
  if(tid<16*DIM) w1s[tid]=W1[tid];
  __syncthreads();
  int e=blockIdx.x*256+tid;
  float xv[DIM];
  #pragma unroll
  for(int j=0;j<DIM;j++) xv[j]=x[(size_t)e*DIM+j];
  float s[16], q[16];
  #pragma unroll
  for(int k=0;k<16;k++){
    float z=0;
    #pragma unroll
    for(int j=0;j<DIM;j++) z+=w1s[k*DIM+j]*xv[j];
    s[k]=z; q[k]=z*z;
  }
  red32_atomic(ws, so, soq, s, q);
}

// ---------------- small-MLP layer-2 stats ----------------
template<int DIM>
__global__ __launch_bounds__(256) void k_small_l2(const float* __restrict__ x,
    const float* __restrict__ W1, const float* __restrict__ W2, float* __restrict__ ws,
    int so1, int so1q, int so2, int so2q){
  __shared__ float w1s[16*DIM];
  __shared__ float w2s[256];
  __shared__ float mi[16][2];
  int tid=threadIdx.x;
  if(tid<16*DIM) w1s[tid]=W1[tid];
  w2s[tid]=W2[tid];
  if(tid<16){
    float m=ws[so1+tid]*(1.0f/4096.0f);
    float v=ws[so1q+tid]*(1.0f/4096.0f)-m*m; if(v<0)v=0;
    mi[tid][0]=m; mi[tid][1]=rsqrtf(v+EPSB);
  }
  __syncthreads();
  int e=blockIdx.x*256+tid;
  float xv[DIM];
  #pragma unroll
  for(int j=0;j<DIM;j++) xv[j]=x[(size_t)e*DIM+j];
  float h1[16];
  #pragma unroll
  for(int h=0;h<16;h++){
    float z=0;
    #pragma unroll
    for(int j=0;j<DIM;j++) z+=w1s[h*DIM+j]*xv[j];
    z=(z-mi[h][0])*mi[h][1];
    h1[h]=z>0?z:0;
  }
  float s[16], q[16];
  #pragma unroll
  for(int k=0;k<16;k++){
    float z=0;
    #pragma unroll
    for(int h=0;h<16;h++) z+=w2s[k*16+h]*h1[h];
    s[k]=z; q[k]=z*z;
  }
  red32_atomic(ws, so2, so2q, s, q);
}

// ---------------- ef assembly: fc-bn + 3 small MLPs -> ef [E,16] ----------------
__device__ __constant__ int EF_BASES[7][2] = {
  {SO_ET1,SO_ET1Q},{SO_ET2,SO_ET2Q},{SO_EL1,SO_EL1Q},{SO_EL2,SO_EL2Q},
  {SO_EV1,SO_EV1Q},{SO_EV2,SO_EV2Q},{SO_FC,SO_FCQ}
};

__global__ __launch_bounds__(256) void k_ef(
    const float* __restrict__ et, const float* __restrict__ etW1, const float* __restrict__ etW2,
    const float* __restrict__ el, const float* __restrict__ elW1, const float* __restrict__ elW2,
    const float* __restrict__ ev, const float* __restrict__ evW1, const float* __restrict__ evW2,
    float* __restrict__ ws){
  __shared__ float w1et[176], w1el[16], w1ev[48];
  __shared__ float w2et[256], w2el[256], w2ev[256];
  __shared__ float mi[7][16][2];
  int tid=threadIdx.x;
  if(tid<176) w1et[tid]=etW1[tid];
  if(tid<16)  w1el[tid]=elW1[tid];
  if(tid<48)  w1ev[tid]=evW1[tid];
  w2et[tid]=etW2[tid]; w2el[tid]=elW2[tid]; w2ev[tid]=evW2[tid];
  if(tid<112){
    int g=tid>>4, h=tid&15;
    float m=ws[EF_BASES[g][0]+h]*(1.0f/4096.0f);
    float v=ws[EF_BASES[g][1]+h]*(1.0f/4096.0f)-m*m; if(v<0)v=0;
    mi[g][h][0]=m; mi[g][h][1]=rsqrtf(v+EPSB);
  }
  __syncthreads();
  int e=blockIdx.x*256+tid;
  float acc[16];
  #pragma unroll
  for(int h=0;h<16;h++){
    float z=ws[F_FCB+(size_t)e*16+h];
    acc[h]=(z-mi[6][h][0])*mi[6][h][1];   // fc: BN, no relu
  }
  { // etype (dim 11)
    float xv[11];
    #pragma unroll
    for(int j=0;j<11;j++) xv[j]=et[(size_t)e*11+j];
    float h1[16];
    #pragma unroll
    for(int h=0;h<16;h++){
      float z=0;
      #pragma unroll
      for(int j=0;j<11;j++) z+=w1et[h*11+j]*xv[j];
      z=(z-mi[0][h][0])*mi[0][h][1];
      h1[h]=z>0?z:0;
    }
    #pragma unroll
    for(int k=0;k<16;k++){
      float z=0;
      #pragma unroll
      for(int h=0;h<16;h++) z+=w2et[k*16+h]*h1[h];
      z=(z-mi[1][k][0])*mi[1][k][1];
      acc[k]+= z>0?z:0;
    }
  }
  { // elen (dim 1)
    float x=el[e];
    float h1[16];
    #pragma unroll
    for(int h=0;h<16;h++){
      float z=x*w1el[h];
      z=(z-mi[2][h][0])*mi[2][h][1];
      h1[h]=z>0?z:0;
    }
    #pragma unroll
    for(int k=0;k<16;k++){
      float z=0;
      #pragma unroll
      for(int h=0;h<16;h++) z+=w2el[k*16+h]*h1[h];
      z=(z-mi[3][k][0])*mi[3][k][1];
      acc[k]+= z>0?z:0;
    }
  }
  { // econv (dim 3)
    float xv[3];
    #pragma unroll
    for(int j=0;j<3;j++) xv[j]=ev[(size_t)e*3+j];
    float h1[16];
    #pragma unroll
    for(int h=0;h<16;h++){
      float z=0;
      #pragma unroll
      for(int j=0;j<3;j++) z+=w1ev[h*3+j]*xv[j];
      z=(z-mi[4][h][0])*mi[4][h][1];
      h1[h]=z>0?z:0;
    }
    #pragma unroll
    for(int k=0;k<16;k++){
      float z=0;
      #pragma unroll
      for(int h=0;h<16;h++) z+=w2ev[k*16+h]*h1[h];
      z=(z-mi[5][k][0])*mi[5][k][1];
      acc[k]+= z>0?z:0;
    }
  }
  #pragma unroll
  for(int h=0;h<16;h++) ws[F_EF+(size_t)e*16+h]=acc[h];
}

// ---------------- proj: node_feat @ ec_Wp.T -> proj [1024,16] ----------------
__global__ __launch_bounds__(256) void k_proj(const float* __restrict__ nf,
    const float* __restrict__ Wp, float* __restrict__ ws){
  __shared__ float wps[4096];
  int tid=threadIdx.x;
  for(int i=tid;i<4096;i+=256) wps[i]=Wp[i];
  __syncthreads();
  int t=blockIdx.x*256+tid;
  int v=t>>4, h=t&15;
  const float* row=nf+(size_t)v*256;
  const float* wr=wps+h*256;
  float z=0;
  for(int c=0;c<256;c++) z+=row[c]*wr[c];
  ws[F_PROJ+t]=z;
}

// ---------------- agg + edgeconv layer1 -> z1ec [E,64] + stats ----------------
__global__ __launch_bounds__(256) void k_agg(const int* __restrict__ src, const int* __restrict__ dst,
    const float* __restrict__ ecW1, float* __restrict__ ws){
  __shared__ float w1s[1024];
  int tid=threadIdx.x;
  for(int i=tid;i<1024;i+=256) w1s[i]=ecW1[i];
  __syncthreads();
  int e=blockIdx.x*256+tid;
  int s=src[e], d=dst[e];
  float a[16];
  #pragma unroll
  for(int h=0;h<16;h++)
    a[h]=ws[F_EF+(size_t)e*16+h]+ws[F_PROJ+(size_t)s*16+h]+ws[F_PROJ+(size_t)d*16+h];
  int lane=tid&63;
  for(int o=0;o<64;o++){
    float z=0;
    #pragma unroll
    for(int h=0;h<16;h++) z+=w1s[o*16+h]*a[h];
    ws[F_Z1EC+(size_t)e*64+o]=z;
    float rs=waveSum(z), rq=waveSum(z*z);
    if(lane==0){ atomicAdd(&ws[SO_G1+o],rs); atomicAdd(&ws[SO_G1Q+o],rq); }
  }
}

// ---------------- edgeconv layer2 -> z2 [E,16] (in F_FCB) + stats ----------------
__global__ __launch_bounds__(256) void k_ec2(const float* __restrict__ ecW2, float* __restrict__ ws){
  __shared__ float w2s[1024];
  __shared__ float mi[64][2];
  int tid=threadIdx.x;
  for(int i=tid;i<1024;i+=256) w2s[i]=ecW2[i];
  if(tid<64){
    float m=ws[SO_G1+tid]*(1.0f/4096.0f);
    float v=ws[SO_G1Q+tid]*(1.0f/4096.0f)-m*m; if(v<0)v=0;
    mi[tid][0]=m; mi[tid][1]=rsqrtf(v+EPSB);
  }
  __syncthreads();
  int e=blockIdx.x*256+tid;
  float acc[16];
  #pragma unroll
  for(int k=0;k<16;k++) acc[k]=0;
  for(int o=0;o<64;o++){
    float z=ws[F_Z1EC+(size_t)e*64+o];
    float h=(z-mi[o][0])*mi[o][1];
    h=h>0?h:0;
    #pragma unroll
    for(int k=0;k<16;k++) acc[k]+=w2s[k*64+o]*h;
  }
  float s[16], q[16];
  #pragma unroll
  for(int k=0;k<16;k++){
    ws[F_FCB+(size_t)e*16+k]=acc[k];
    s[k]=acc[k]; q[k]=acc[k]*acc[k];
  }
  red32_atomic(ws, SO_G2, SO_G2Q, s, q);
}

// ---------------- edge_feature fill [4,1025,16] ----------------
__global__ __launch_bounds__(256) void k_ef2(float* __restrict__ ws){
  int t=blockIdx.x*256+threadIdx.x;
  if(t>=4*1025*16) return;
  int h=t&15, r=t>>4;
  int b=r/1025, pos=r%1025;
  float v=0;
  if(pos<1024){
    int e=b*1024+pos;
    float z=ws[F_FCB+(size_t)e*16+h];
    float m=ws[SO_G2+h]*(1.0f/4096.0f);
    float va=ws[SO_G2Q+h]*(1.0f/4096.0f)-m*m; if(va<0)va=0;
    v=(z-m)*rsqrtf(va+EPSB);
    v=v>0?v:0;
  }
  ws[F_EDGEF+t]=v;
}

// ---------------- main per-pair kernel: interior output ----------------
__global__ __launch_bounds__(256) void k_pair(const float* __restrict__ ab,
    const int* __restrict__ sd, const float* __restrict__ ang, const float* __restrict__ cen,
    const int* __restrict__ ep, const float* __restrict__ sdemb, const float* __restrict__ edisw,
    const float* __restrict__ angW1, const float* __restrict__ angW2,
    const float* __restrict__ cenW1, const float* __restrict__ cenW2,
    const float* __restrict__ ws, float* __restrict__ out){
  __shared__ float wd[1280];
  __shared__ float w2a[256], w2c[256];
  __shared__ float Aa[16], Ac[16], m2a[16], i2a[16], m2c[16], i2c[16];
  __shared__ float muA, muC, varA, varC;
  int tid=threadIdx.x;
  for(int i=tid;i<1280;i+=256) wd[i]=edisw[i];
  w2a[tid]=angW2[tid]; w2c[tid]=cenW2[tid];
  if(tid==0){
    float s=ws[SO_ANGX], q=ws[SO_ANGX+1];
    float mu=s*(1.0f/262144.0f);
    float v=q*(1.0f/262144.0f)-mu*mu; if(v<0)v=0;
    muA=mu; varA=v;
    s=ws[SO_CENX]; q=ws[SO_CENX+1];
    mu=s*(1.0f/262144.0f);
    v=q*(1.0f/262144.0f)-mu*mu; if(v<0)v=0;
    muC=mu; varC=v;
  }
  __syncthreads();
  if(tid<16){
    float w=angW1[tid]; Aa[tid]=w/sqrtf(varA*w*w+EPSB);
    float m=ws[SO_ANG2+tid]*(1.0f/262144.0f);
    float v=ws[SO_ANG2Q+tid]*(1.0f/262144.0f)-m*m; if(v<0)v=0;
    m2a[tid]=m; i2a[tid]=rsqrtf(v+EPSB);
  } else if(tid<32){
    int h=tid-16;
    float w=cenW1[h]; Ac[h]=w/sqrtf(varC*w*w+EPSB);
    float m=ws[SO_CEN2+h]*(1.0f/262144.0f);
    float v=ws[SO_CEN2Q+h]*(1.0f/262144.0f)-m*m; if(v<0)v=0;
    m2c[h]=m; i2c[h]=rsqrtf(v+EPSB);
  }
  __syncthreads();
  int t=blockIdx.x*256+tid;            // b,i,j
  int b=t>>16, rem=t&65535, i=rem>>8, j=rem&255;
  int sdv=sd[t];
  float xa=ang[t], xc0=cen[t];
  float acc[16];
  const float* se=sdemb+(size_t)sdv*16;
  #pragma unroll
  for(int k=0;k<16;k++) acc[k]=se[k];
  { // angle MLP
    float xc=xa-muA;
    float h1[16];
    #pragma unroll
    for(int h=0;h<16;h++){ float v=xc*Aa[h]; h1[h]=v>0?v:0; }
    #pragma unroll
    for(int k=0;k<16;k++){
      float z=0;
      #pragma unroll
      for(int h=0;h<16;h++) z+=w2a[k*16+h]*h1[h];
      float r=(z-m2a[k])*i2a[k];
      acc[k]+= r>0?r:0;
    }
  }
  { // centroid MLP
    float xc=xc0-muC;
    float h1[16];
    #pragma unroll
    for(int h=0;h<16;h++){ float v=xc*Ac[h]; h1[h]=v>0?v:0; }
    #pragma unroll
    for(int k=0;k<16;k++){
      float z=0;
      #pragma unroll
      for(int h=0;h<16;h++) z+=w2c[k*16+h]*h1[h];
      float r=(z-m2c[k])*i2c[k];
      acc[k]+= r>0?r:0;
    }
  }
  { // multi-hop edge bias
    int sdm = sdv==0 ? 1 : sdv;
    if(sdm>1) sdm-=1;
    if(sdm>5) sdm=5;
    float inv=1.0f/((float)sdm+1e-6f);
    float eb[16];
    #pragma unroll
    for(int k=0;k<16;k++) eb[k]=0;
    const float* EF=ws+F_EDGEF+(size_t)b*1025*16;
    #pragma unroll
    for(int d=0;d<5;d++){
      int idx=ep[(size_t)t*5+d];
      const float* r=EF+(size_t)idx*16;
      float e16[16];
      #pragma unroll
      for(int k=0;k<16;k+=4){
        float4 v=*(const float4*)(r+k);
        e16[k]=v.x; e16[k+1]=v.y; e16[k+2]=v.z; e16[k+3]=v.w;
      }
      const float* wdd=wd+d*256;
      #pragma unroll
      for(int h=0;h<16;h++){
        float evv=e16[h];
        #pragma unroll
        for(int k=0;k<16;k++) eb[k]+=evv*wdd[h*16+k];
      }
    }
    #pragma unroll
    for(int k=0;k<16;k++) acc[k]+=eb[k]*inv;
  }
  float base2=2.0f*ab[(size_t)b*66049+(size_t)(i+1)*257+(j+1)];
  #pragma unroll
  for(int k=0;k<16;k++)
    out[(((size_t)b*16+k)*257+(i+1))*257+(j+1)]=acc[k]+base2;
}

// ---------------- borders: row 0 and col 0 ----------------
__global__ __launch_bounds__(256) void k_border(const float* __restrict__ ab,
    const float* __restrict__ virt, float* __restrict__ out){
  int t=blockIdx.x*256+threadIdx.x;
  if(t>=4*16*513) return;
  int idx=t%513, bh=t/513;
  int b=bh>>4, h=bh&15;
  float v=virt[h];
  if(idx<257){
    out[(((size_t)b*16+h)*257)*257+idx]=2.0f*ab[(size_t)b*66049+idx]+v;
  } else {
    int p=idx-256;   // 1..256
    out[(((size_t)b*16+h)*257+p)*257]=2.0f*ab[(size_t)b*66049+(size_t)p*257]+v;
  }
}

extern "C" void kernel_launch(void* const* d_in, const int* in_sizes, int n_in,
                              void* d_out, int out_size, void* d_ws, size_t ws_size,
                              hipStream_t stream) {
  const float* ab    =(const float*)d_in[0];
  const int*   sdist =(const int*)  d_in[1];
  const float* ang   =(const float*)d_in[2];
  const float* cen   =(const float*)d_in[3];
  const int*   ep    =(const int*)  d_in[4];
  const float* edata =(const float*)d_in[5];
  const float* etype =(const float*)d_in[6];
  const float* elen  =(const float*)d_in[7];
  const float* econv =(const float*)d_in[8];
  const int*   src   =(const int*)  d_in[10];
  const int*   dst   =(const int*)  d_in[11];
  const float* nf    =(const float*)d_in[12];
  const float* sdemb =(const float*)d_in[13];
  const float* virt  =(const float*)d_in[14];
  const float* angW1 =(const float*)d_in[15];
  const float* angW2 =(const float*)d_in[16];
  const float* cenW1 =(const float*)d_in[17];
  const float* cenW2 =(const float*)d_in[18];
  const float* etW1  =(const float*)d_in[19];
  const float* etW2  =(const float*)d_in[20];
  const float* elW1  =(const float*)d_in[21];
  const float* elW2  =(const float*)d_in[22];
  const float* evW1  =(const float*)d_in[23];
  const float* evW2  =(const float*)d_in[24];
  const float* c1w   =(const float*)d_in[25];
  const float* c2w   =(const float*)d_in[26];
  const float* c3w   =(const float*)d_in[27];
  const float* fcw   =(const float*)d_in[28];
  const float* edisw =(const float*)d_in[29];
  const float* ecWp  =(const float*)d_in[30];
  const float* ecW1  =(const float*)d_in[31];
  const float* ecW2  =(const float*)d_in[32];
  float* ws=(float*)d_ws;
  float* out=(float*)d_out;

  hipMemsetAsync(d_ws, 0, STATS_FLOATS*sizeof(float), stream);

  k_scalar_stats<<<256,256,0,stream>>>(ang,cen,ws);
  k_ac_l2stats<<<128,256,0,stream>>>(ang,angW1,angW2,ws,SO_ANGX,SO_ANG2,SO_ANG2Q);
  k_ac_l2stats<<<128,256,0,stream>>>(cen,cenW1,cenW2,ws,SO_CENX,SO_CEN2,SO_CEN2Q);

  k_conv1<<<512,64,0,stream>>>(edata,c1w,ws);
  k_conv2<<<2048,128,0,stream>>>(c2w,ws);
  k_conv3<<<2048,256,0,stream>>>(c3w,ws);
  k_pool<<<4096,256,0,stream>>>(ws);
  k_fc<<<256,256,0,stream>>>(fcw,ws);

  k_small_l1<11><<<16,256,0,stream>>>(etype,etW1,ws,SO_ET1,SO_ET1Q);
  k_small_l1<1> <<<16,256,0,stream>>>(elen ,elW1,ws,SO_EL1,SO_EL1Q);
  k_small_l1<3> <<<16,256,0,stream>>>(econv,evW1,ws,SO_EV1,SO_EV1Q);
  k_small_l2<11><<<16,256,0,stream>>>(etype,etW1,etW2,ws,SO_ET1,SO_ET1Q,SO_ET2,SO_ET2Q);
  k_small_l2<1> <<<16,256,0,stream>>>(elen ,elW1,elW2,ws,SO_EL1,SO_EL1Q,SO_EL2,SO_EL2Q);
  k_small_l2<3> <<<16,256,0,stream>>>(econv,evW1,evW2,ws,SO_EV1,SO_EV1Q,SO_EV2,SO_EV2Q);

  k_ef<<<16,256,0,stream>>>(etype,etW1,etW2,elen,elW1,elW2,econv,evW1,evW2,ws);
  k_proj<<<64,256,0,stream>>>(nf,ecWp,ws);
  k_agg<<<16,256,0,stream>>>(src,dst,ecW1,ws);
  k_ec2<<<16,256,0,stream>>>(ecW2,ws);
  k_ef2<<<257,256,0,stream>>>(ws);

  k_pair<<<1024,256,0,stream>>>(ab,sdist,ang,cen,ep,sdemb,edisw,angW1,angW2,cenW1,cenW2,ws,out);
  k_border<<<129,256,0,stream>>>(ab,virt,out);
}

// Round 3
// 404.928 us; speedup vs baseline: 2.0744x; 1.7687x over previous
//
#include <hip/hip_runtime.h>

#define EPSB 1e-5f
#define B_ 4
#define N_ 256
#define H_ 16
#define D_ 5
#define E_ 4096
#define M_PAIR (B_*N_*N_)   // 262144

typedef __attribute__((ext_vector_type(8))) short short8;
typedef __attribute__((ext_vector_type(4))) float f32x4;

// ---- stats slot offsets (floats) in ws ----
enum {
  SO_ANGX = 0,               // ang sum, ang sq, cen sum, cen sq
  SO_CENX = 2,
  SO_ANG2 = 16,  SO_ANG2Q = 32,
  SO_CEN2 = 48,  SO_CEN2Q = 64,
  SO_C1   = 96,  SO_C1Q   = 160,
  SO_C2   = 224, SO_C2Q   = 352,
  SO_C3   = 480, SO_C3Q   = 736,
  SO_FC   = 992, SO_FCQ   = 1008,
  SO_ET1  = 1024, SO_ET1Q = 1040, SO_ET2 = 1056, SO_ET2Q = 1072,
  SO_EL1  = 1088, SO_EL1Q = 1104, SO_EL2 = 1120, SO_EL2Q = 1136,
  SO_EV1  = 1152, SO_EV1Q = 1168, SO_EV2 = 1184, SO_EV2Q = 1200,
  SO_G1   = 1216, SO_G1Q  = 1280,
  SO_G2   = 1344, SO_G2Q  = 1360,
  STATS_FLOATS = 2048
};

// ---- buffer offsets (floats) ----
// y1: [E][20][64] fp32 (then aliased by y3 [E][20][256])
static constexpr size_t F_Y13  = 2048;
static constexpr size_t F_Y2   = F_Y13 + 20971520;     // [E][20][128] fp32
static constexpr size_t F_POOL = F_Y2 + 10485760;      // E*256
static constexpr size_t F_FCB  = F_POOL + 1048576;     // E*16 (fc out, later z2 of edgeconv)
static constexpr size_t F_EF   = F_FCB + 65536;        // E*16
static constexpr size_t F_PROJ = F_EF + 65536;         // 1024*16
static constexpr size_t F_Z1EC = F_PROJ + 16384;       // E*64
static constexpr size_t F_EDGEF= F_Z1EC + 262144;      // 4*1025*16
static constexpr size_t F_WT2  = F_EDGEF + 65600;      // 128*192 bf16 = 12288 floats
static constexpr size_t F_WT3  = F_WT2 + 12288;        // 256*384 bf16 = 49152 floats

__device__ __forceinline__ float waveSum(float v){
  #pragma unroll
  for(int o=32;o;o>>=1) v += __shfl_down(v,o);
  return v;
}

__device__ __forceinline__ ushort f2bf(float f){
  uint u = __float_as_uint(f);
  uint r = (u + 0x7FFF + ((u>>16)&1)) >> 16;
  return (ushort)r;
}

// block = 256 threads (4 waves). Reduce 16 sums + 16 sumsqs, atomicAdd to ws.
__device__ __forceinline__ void red32_atomic(float* ws, int so, int soq, float* s, float* q){
  __shared__ float red[4][32];
  int tid=threadIdx.x, lane=tid&63, wid=tid>>6;
  #pragma unroll
  for(int k=0;k<16;k++){
    float rs=waveSum(s[k]), rq=waveSum(q[k]);
    if(lane==0){ red[wid][k]=rs; red[wid][16+k]=rq; }
  }
  __syncthreads();
  if(tid<32){
    float t=red[0][tid]+red[1][tid]+red[2][tid]+red[3][tid];
    atomicAdd(&ws[tid<16 ? so+tid : soq+(tid-16)], t);
  }
}

// ---------------- scalar stats of angle & centroid ----------------
__global__ __launch_bounds__(256) void k_scalar_stats(const float* __restrict__ ang,
    const float* __restrict__ cen, float* __restrict__ st){
  int tid = blockIdx.x*256 + threadIdx.x;
  float sa=0, qa=0, sc=0, qc=0;
  for(int i=tid; i<M_PAIR; i += gridDim.x*256){
    float a=ang[i], c=cen[i];
    sa+=a; qa+=a*a; sc+=c; qc+=c*c;
  }
  __shared__ float red[4][4];
  int lane=threadIdx.x&63, wid=threadIdx.x>>6;
  sa=waveSum(sa); qa=waveSum(qa); sc=waveSum(sc); qc=waveSum(qc);
  if(lane==0){ red[wid][0]=sa; red[wid][1]=qa; red[wid][2]=sc; red[wid][3]=qc; }
  __syncthreads();
  if(threadIdx.x<4){
    float t=red[0][threadIdx.x]+red[1][threadIdx.x]+red[2][threadIdx.x]+red[3][threadIdx.x];
    atomicAdd(&st[threadIdx.x], t);
  }
}

// ---------------- layer-2 stats for angle/cent MLPs ----------------
__global__ __launch_bounds__(256) void k_ac_l2stats(const float* __restrict__ x,
    const float* __restrict__ W1, const float* __restrict__ W2,
    float* __restrict__ st, int soX, int soS, int soQ){
  __shared__ float w2s[256];
  __shared__ float Ah[16];
  __shared__ float mu_s, var_s;
  int tid=threadIdx.x;
  w2s[tid]=W2[tid];
  if(tid==0){
    float s=st[soX], qq=st[soX+1];
    float mu=s*(1.0f/262144.0f);
    float v=qq*(1.0f/262144.0f)-mu*mu; if(v<0)v=0;
    mu_s=mu; var_s=v;
  }
  __syncthreads();
  if(tid<16){ float w=W1[tid]; Ah[tid]=w/sqrtf(var_s*w*w+EPSB); }
  __syncthreads();
  float s[16], q[16];
  #pragma unroll
  for(int k=0;k<16;k++){ s[k]=0; q[k]=0; }
  for(int i=blockIdx.x*256+tid; i<M_PAIR; i+=gridDim.x*256){
    float xc=x[i]-mu_s;
    float h1[16];
    #pragma unroll
    for(int h=0;h<16;h++){ float t=xc*Ah[h]; h1[h]=t>0?t:0; }
    #pragma unroll
    for(int k=0;k<16;k++){
      float z=0;
      #pragma unroll
      for(int h=0;h<16;h++) z+=w2s[k*16+h]*h1[h];
      s[k]+=z; q[k]+=z*z;
    }
  }
  red32_atomic(st, soS, soQ, s, q);
}

// ---------------- weight prep: transpose conv weights to bf16 [o][t*C+c] ----------------
__global__ __launch_bounds__(256) void k_wprep(const float* __restrict__ c2w,
    const float* __restrict__ c3w, ushort* __restrict__ wt2, ushort* __restrict__ wt3){
  int t = blockIdx.x*256 + threadIdx.x;
  if(t < 128*192){
    int o=t/192, k=t%192, tt=k/64, c=k%64;
    wt2[o*192+k] = f2bf(c2w[(o*64+c)*3+tt]);
  } else {
    int u=t-128*192;
    if(u<256*384){
      int o=u/384, k=u%384, tt=k/128, c=k%128;
      wt3[o*384+k] = f2bf(c3w[(o*128+c)*3+tt]);
    }
  }
}

// ---------------- conv1: [E,12,20] -> y1 [E][20][64] + stats ----------------
__global__ __launch_bounds__(64) void k_conv1(const float* __restrict__ ed,
    const float* __restrict__ w, float* __restrict__ ws){
  __shared__ float wsh[64*36];
  __shared__ float xs[8][12][20];
  int tid=threadIdx.x;
  for(int i=tid;i<64*36;i+=64) wsh[i]=w[i];
  int e0=blockIdx.x*8;
  for(int i=tid;i<8*240;i+=64){
    int e=i/240, r=i%240, l=r/12, c=r%12;
    xs[e][c][l]=ed[(size_t)(e0+e)*240+r];
  }
  __syncthreads();
  int o=tid;
  float* y1=ws+F_Y13;
  float ssum=0, ssq=0;
  for(int e=0;e<8;e++){
    float acc[20];
    #pragma unroll
    for(int l=0;l<20;l++) acc[l]=0;
    for(int c=0;c<12;c++){
      float w0=wsh[o*36+c*3], w1=wsh[o*36+c*3+1], w2=wsh[o*36+c*3+2];
      const float* xr=xs[e][c];
      #pragma unroll
      for(int l=0;l<20;l++){
        acc[l]=fmaf(w1,xr[l],acc[l]);
        if(l>0)  acc[l]=fmaf(w0,xr[l-1],acc[l]);
        if(l<19) acc[l]=fmaf(w2,xr[l+1],acc[l]);
      }
    }
    size_t base=((size_t)(e0+e)*20)*64;
    #pragma unroll
    for(int l=0;l<20;l++){ y1[base+(size_t)l*64+o]=acc[l]; ssum+=acc[l]; ssq+=acc[l]*acc[l]; }
  }
  atomicAdd(&ws[SO_C1+o], ssum);
  atomicAdd(&ws[SO_C1Q+o], ssq);
}

// ---------------- MFMA conv (conv2/conv3): bn+lrelu(yin) conv w -> yout + stats ----
// yin: [E][20][CIN] fp32.  wt: bf16 [OUT][3*CIN] (k = t*CIN + c).  yout: [E][20][OUT] fp32.
// Block: 256 thr (4 waves), EPB edges -> M = EPB*20 rows, N = OUT cols, K = 3*CIN.
template<int CIN, int OUT, int EPB>
__global__ __launch_bounds__(256) void k_convmf(
    const float* __restrict__ yin, const ushort* __restrict__ wt,
    float* __restrict__ yout, float* __restrict__ ws,
    int soIn, int soInQ, int soOut, int soOutQ)
{
  constexpr int K = CIN*3;
  constexpr int KSTEPS = K/32;
  constexpr int M = EPB*20;
  constexpr int ROWT = M/16;
  constexpr int WCOLT = OUT/64;            // col-tiles per wave (4 waves)
  constexpr int ROWS = EPB*22;             // zero-padded length dim
  constexpr int RB = CIN*2;                // row bytes in LDS
  __shared__ ushort xs[ROWS*CIN];
  __shared__ float mi[CIN][2];
  int tid = threadIdx.x;
  for(int c=tid; c<CIN; c+=256){
    float m=ws[soIn+c]*(1.0f/81920.0f);
    float v=ws[soInQ+c]*(1.0f/81920.0f)-m*m; if(v<0)v=0;
    mi[c][0]=m; mi[c][1]=rsqrtf(v+EPSB);
  }
  // zero pad rows lp=0,21 (XOR swizzle is a within-row permutation; linear zero-fill ok)
  uint* xs32 = (uint*)xs;
  for(int i=tid; i<EPB*2*(CIN/2); i+=256){
    int e=i/(CIN), r=i%(CIN); int lp = (r < CIN/2)? 0:21; int cw = r%(CIN/2);
    xs32[(e*22+lp)*(CIN/2)+cw]=0;
  }
  __syncthreads();
  // stage: read yin, bn+lrelu, bf16, swizzled LDS write
  int e0 = blockIdx.x*EPB;
  const float* src = yin + (size_t)e0*20*CIN;
  for(int i=tid; i<EPB*20*(CIN/4); i+=256){
    int c4 = i%(CIN/4); int rl = i/(CIN/4);      // rl = e*20+l
    int c = c4*4;
    float4 v = *(const float4*)(src + (size_t)rl*CIN + c);
    float f0=(v.x-mi[c  ][0])*mi[c  ][1]; f0= f0>=0?f0:0.01f*f0;
    float f1=(v.y-mi[c+1][0])*mi[c+1][1]; f1= f1>=0?f1:0.01f*f1;
    float f2=(v.z-mi[c+2][0])*mi[c+2][1]; f2= f2>=0?f2:0.01f*f2;
    float f3=(v.w-mi[c+3][0])*mi[c+3][1]; f3= f3>=0?f3:0.01f*f3;
    int e = rl/20, l=rl%20;
    int row = e*22 + l + 1;
    uint byteoff = (uint)row*RB + (((uint)c*2) ^ (uint)((row&7)<<4));
    uint pk0 = (uint)f2bf(f0) | ((uint)f2bf(f1)<<16);
    uint pk1 = (uint)f2bf(f2) | ((uint)f2bf(f3)<<16);
    *(uint2*)((char*)xs + byteoff) = make_uint2(pk0,pk1);
  }
  __syncthreads();

  int lane = tid&63, wid = tid>>6;
  int l16 = lane&15, lhi = lane>>4;
  int colbase = wid*(OUT/4);
  f32x4 acc[ROWT][WCOLT];
  #pragma unroll
  for(int m=0;m<ROWT;m++)
    #pragma unroll
    for(int n=0;n<WCOLT;n++) acc[m][n]=(f32x4){0,0,0,0};
  int rowc[ROWT];
  #pragma unroll
  for(int m=0;m<ROWT;m++){ int r=m*16+l16; rowc[m]=(r/20)*22 + (r%20); }
  const ushort* wbase[WCOLT];
  #pragma unroll
  for(int n=0;n<WCOLT;n++) wbase[n] = wt + (size_t)(colbase + n*16 + l16)*K + lhi*8;

  #pragma unroll
  for(int ks=0; ks<KSTEPS; ks++){
    int t  = ks/(CIN/32);                  // tap 0..2
    int c0 = (ks%(CIN/32))*32 + lhi*8;     // within-tap channel base for this lane
    short8 aF[ROWT], bF[WCOLT];
    #pragma unroll
    for(int m=0;m<ROWT;m++){
      int row = rowc[m] + t + 1;           // stored lp = l + t  (pad shift +1, tap shift -1)
      // NOTE: rowc holds e*22+l, stored index for x[l+t-1] is e*22 + (l+t-1) + 1 = rowc + t
      row = rowc[m] + t;
      uint off = (uint)row*RB + (((uint)c0*2) ^ (uint)((row&7)<<4));
      aF[m] = *(const short8*)((char*)xs + off);
    }
    #pragma unroll
    for(int n=0;n<WCOLT;n++) bF[n] = *(const short8*)(wbase[n] + ks*32);
    #pragma unroll
    for(int m=0;m<ROWT;m++)
      #pragma unroll
      for(int n=0;n<WCOLT;n++)
        acc[m][n]=__builtin_amdgcn_mfma_f32_16x16x32_bf16(aF[m],bF[n],acc[m][n],0,0,0);
  }

  // per-output-channel stats
  #pragma unroll
  for(int n=0;n<WCOLT;n++){
    float s=0,q=0;
    #pragma unroll
    for(int m=0;m<ROWT;m++)
      #pragma unroll
      for(int j=0;j<4;j++){ float a=acc[m][n][j]; s+=a; q+=a*a; }
    s += __shfl_xor(s,16); s += __shfl_xor(s,32);
    q += __shfl_xor(q,16); q += __shfl_xor(q,32);
    if(lhi==0){
      int o = colbase+n*16+l16;
      atomicAdd(&ws[soOut+o], s);
      atomicAdd(&ws[soOutQ+o], q);
    }
  }
  // store yout [R][OUT], R global = blockIdx*M + m*16 + lhi*4 + j
  float* dst = yout + (size_t)blockIdx.x*M*OUT;
  #pragma unroll
  for(int m=0;m<ROWT;m++)
    #pragma unroll
    for(int j=0;j<4;j++){
      int R = m*16 + lhi*4 + j;
      #pragma unroll
      for(int n=0;n<WCOLT;n++)
        dst[(size_t)R*OUT + colbase + n*16 + l16] = acc[m][n][j];
    }
}

// ---------------- pool: mean_l lrelu(bn(y3)) -> pooled [E,256] ----------------
// y3 layout [E][20][256]
__global__ __launch_bounds__(256) void k_pool(float* __restrict__ ws){
  int t=blockIdx.x*256+threadIdx.x;   // e*256+o
  int o=t&255, e=t>>8;
  float m=ws[SO_C3+o]*(1.0f/81920.0f);
  float v=ws[SO_C3Q+o]*(1.0f/81920.0f)-m*m; if(v<0)v=0;
  float inv=rsqrtf(v+EPSB);
  const float* y3=ws+F_Y13+(size_t)e*20*256+o;
  float s=0;
  #pragma unroll
  for(int l=0;l<20;l++){
    float x=(y3[(size_t)l*256]-m)*inv;
    s += x>=0.f? x : 0.01f*x;
  }
  ws[F_POOL+t]=s*(1.0f/20.0f);
}

// ---------------- fc: pooled @ curv_fc.T -> fcb [E,16] + stats ----------------
__global__ __launch_bounds__(256) void k_fc(const float* __restrict__ fcw, float* __restrict__ ws){
  __shared__ float ps[16][260];
  __shared__ float red[4][32];
  int tid=threadIdx.x;
  int e0=blockIdx.x*16;
  for(int i=tid;i<4096;i+=256){
    ps[i>>8][i&255]=ws[F_POOL+(size_t)(e0+(i>>8))*256+(i&255)];
  }
  __syncthreads();
  int e=tid>>4, h=tid&15;
  const float* wr=fcw+(size_t)h*256;
  float z=0;
  for(int c=0;c<256;c++) z+=ps[e][c]*wr[c];
  ws[F_FCB+(size_t)(e0+e)*16+h]=z;
  float s=z, q=z*z;
  #pragma unroll
  for(int o=16;o<64;o<<=1){ s+=__shfl_down(s,o); q+=__shfl_down(q,o); }
  int lane=tid&63, wid=tid>>6;
  if(lane<16){ red[wid][lane]=s; red[wid][16+lane]=q; }
  __syncthreads();
  if(tid<32){
    float v=red[0][tid]+red[1][tid]+red[2][tid]+red[3][tid];
    atomicAdd(&ws[tid<16? SO_FC+tid : SO_FCQ+(tid-16)], v);
  }
}

// ---------------- small-MLP layer-1 stats ----------------
template<int DIM>
__global__ __launch_bounds__(256) void k_small_l1(const float* __restrict__ x,
    const float* __restrict__ W1, float* __restrict__ ws, int so, int soq){
  __shared__ float w1s[16*DIM];
  int tid=threadIdx.x;
  if(tid<16*DIM) w1s[tid]=W1[tid];
  __syncthreads();
  int e=blockIdx.x*256+tid;
  float xv[DIM];
  #pragma unroll
  for(int j=0;j<DIM;j++) xv[j]=x[(size_t)e*DIM+j];
  float s[16], q[16];
  #pragma unroll
  for(int k=0;k<16;k++){
    float z=0;
    #pragma unroll
    for(int j=0;j<DIM;j++) z+=w1s[k*DIM+j]*xv[j];
    s[k]=z; q[k]=z*z;
  }
  red32_atomic(ws, so, soq, s, q);
}

// ---------------- small-MLP layer-2 stats ----------------
template<int DIM>
__global__ __launch_bounds__(256) void k_small_l2(const float* __restrict__ x,
    const float* __restrict__ W1, const float* __restrict__ W2, float* __restrict__ ws,
    int so1, int so1q, int so2, int so2q){
  __shared__ float w1s[16*DIM];
  __shared__ float w2s[256];
  __shared__ float mi[16][2];
  int tid=threadIdx.x;
  if(tid<16*DIM) w1s[tid]=W1[tid];
  w2s[tid]=W2[tid];
  if(tid<16){
    float m=ws[so1+tid]*(1.0f/4096.0f);
    float v=ws[so1q+tid]*(1.0f/4096.0f)-m*m; if(v<0)v=0;
    mi[tid][0]=m; mi[tid][1]=rsqrtf(v+EPSB);
  }
  __syncthreads();
  int e=blockIdx.x*256+tid;
  float xv[DIM];
  #pragma unroll
  for(int j=0;j<DIM;j++) xv[j]=x[(size_t)e*DIM+j];
  float h1[16];
  #pragma unroll
  for(int h=0;h<16;h++){
    float z=0;
    #pragma unroll
    for(int j=0;j<DIM;j++) z+=w1s[h*DIM+j]*xv[j];
    z=(z-mi[h][0])*mi[h][1];
    h1[h]=z>0?z:0;
  }
  float s[16], q[16];
  #pragma unroll
  for(int k=0;k<16;k++){
    float z=0;
    #pragma unroll
    for(int h=0;h<16;h++) z+=w2s[k*16+h]*h1[h];
    s[k]=z; q[k]=z*z;
  }
  red32_atomic(ws, so2, so2q, s, q);
}

// ---------------- ef assembly: fc-bn + 3 small MLPs -> ef [E,16] ----------------
__device__ __constant__ int EF_BASES[7][2] = {
  {SO_ET1,SO_ET1Q},{SO_ET2,SO_ET2Q},{SO_EL1,SO_EL1Q},{SO_EL2,SO_EL2Q},
  {SO_EV1,SO_EV1Q},{SO_EV2,SO_EV2Q},{SO_FC,SO_FCQ}
};

__global__ __launch_bounds__(256) void k_ef(
    const float* __restrict__ et, const float* __restrict__ etW1, const float* __restrict__ etW2,
    const float* __restrict__ el, const float* __restrict__ elW1, const float* __restrict__ elW2,
    const float* __restrict__ ev, const float* __restrict__ evW1, const float* __restrict__ evW2,
    float* __restrict__ ws){
  __shared__ float w1et[176], w1el[16], w1ev[48];
  __shared__ float w2et[256], w2el[256], w2ev[256];
  __shared__ float mi[7][16][2];
  int tid=threadIdx.x;
  if(tid<176) w1et[tid]=etW1[tid];
  if(tid<16)  w1el[tid]=elW1[tid];
  if(tid<48)  w1ev[tid]=evW1[tid];
  w2et[tid]=etW2[tid]; w2el[tid]=elW2[tid]; w2ev[tid]=evW2[tid];
  if(tid<112){
    int g=tid>>4, h=tid&15;
    float m=ws[EF_BASES[g][0]+h]*(1.0f/4096.0f);
    float v=ws[EF_BASES[g][1]+h]*(1.0f/4096.0f)-m*m; if(v<0)v=0;
    mi[g][h][0]=m; mi[g][h][1]=rsqrtf(v+EPSB);
  }
  __syncthreads();
  int e=blockIdx.x*256+tid;
  float acc[16];
  #pragma unroll
  for(int h=0;h<16;h++){
    float z=ws[F_FCB+(size_t)e*16+h];
    acc[h]=(z-mi[6][h][0])*mi[6][h][1];   // fc: BN, no relu
  }
  { // etype (dim 11)
    float xv[11];
    #pragma unroll
    for(int j=0;j<11;j++) xv[j]=et[(size_t)e*11+j];
    float h1[16];
    #pragma unroll
    for(int h=0;h<16;h++){
      float z=0;
      #pragma unroll
      for(int j=0;j<11;j++) z+=w1et[h*11+j]*xv[j];
      z=(z-mi[0][h][0])*mi[0][h][1];
      h1[h]=z>0?z:0;
    }
    #pragma unroll
    for(int k=0;k<16;k++){
      float z=0;
      #pragma unroll
      for(int h=0;h<16;h++) z+=w2et[k*16+h]*h1[h];
      z=(z-mi[1][k][0])*mi[1][k][1];
      acc[k]+= z>0?z:0;
    }
  }
  { // elen (dim 1)
    float x=el[e];
    float h1[16];
    #pragma unroll
    for(int h=0;h<16;h++){
      float z=x*w1el[h];
      z=(z-mi[2][h][0])*mi[2][h][1];
      h1[h]=z>0?z:0;
    }
    #pragma unroll
    for(int k=0;k<16;k++){
      float z=0;
      #pragma unroll
      for(int h=0;h<16;h++) z+=w2el[k*16+h]*h1[h];
      z=(z-mi[3][k][0])*mi[3][k][1];
      acc[k]+= z>0?z:0;
    }
  }
  { // econv (dim 3)
    float xv[3];
    #pragma unroll
    for(int j=0;j<3;j++) xv[j]=ev[(size_t)e*3+j];
    float h1[16];
    #pragma unroll
    for(int h=0;h<16;h++){
      float z=0;
      #pragma unroll
      for(int j=0;j<3;j++) z+=w1ev[h*3+j]*xv[j];
      z=(z-mi[4][h][0])*mi[4][h][1];
      h1[h]=z>0?z:0;
    }
    #pragma unroll
    for(int k=0;k<16;k++){
      float z=0;
      #pragma unroll
      for(int h=0;h<16;h++) z+=w2ev[k*16+h]*h1[h];
      z=(z-mi[5][k][0])*mi[5][k][1];
      acc[k]+= z>0?z:0;
    }
  }
  #pragma unroll
  for(int h=0;h<16;h++) ws[F_EF+(size_t)e*16+h]=acc[h];
}

// ---------------- proj: node_feat @ ec_Wp.T -> proj [1024,16] ----------------
__global__ __launch_bounds__(256) void k_proj(const float* __restrict__ nf,
    const float* __restrict__ Wp, float* __restrict__ ws){
  __shared__ float wps[4096];
  int tid=threadIdx.x;
  for(int i=tid;i<4096;i+=256) wps[i]=Wp[i];
  __syncthreads();
  int t=blockIdx.x*256+tid;
  int v=t>>4, h=t&15;
  const float* row=nf+(size_t)v*256;
  const float* wr=wps+h*256;
  float z=0;
  for(int c=0;c<256;c++) z+=row[c]*wr[c];
  ws[F_PROJ+t]=z;
}

// ---------------- agg + edgeconv layer1 -> z1ec [E,64] + stats ----------------
__global__ __launch_bounds__(256) void k_agg(const int* __restrict__ src, const int* __restrict__ dst,
    const float* __restrict__ ecW1, float* __restrict__ ws){
  __shared__ float w1s[1024];
  int tid=threadIdx.x;
  for(int i=tid;i<1024;i+=256) w1s[i]=ecW1[i];
  __syncthreads();
  int e=blockIdx.x*256+tid;
  int s=src[e], d=dst[e];
  float a[16];
  #pragma unroll
  for(int h=0;h<16;h++)
    a[h]=ws[F_EF+(size_t)e*16+h]+ws[F_PROJ+(size_t)s*16+h]+ws[F_PROJ+(size_t)d*16+h];
  int lane=tid&63;
  for(int o=0;o<64;o++){
    float z=0;
    #pragma unroll
    for(int h=0;h<16;h++) z+=w1s[o*16+h]*a[h];
    ws[F_Z1EC+(size_t)e*64+o]=z;
    float rs=waveSum(z), rq=waveSum(z*z);
    if(lane==0){ atomicAdd(&ws[SO_G1+o],rs); atomicAdd(&ws[SO_G1Q+o],rq); }
  }
}

// ---------------- edgeconv layer2 -> z2 [E,16] (in F_FCB) + stats ----------------
__global__ __launch_bounds__(256) void k_ec2(const float* __restrict__ ecW2, float* __restrict__ ws){
  __shared__ float w2s[1024];
  __shared__ float mi[64][2];
  int tid=threadIdx.x;
  for(int i=tid;i<1024;i+=256) w2s[i]=ecW2[i];
  if(tid<64){
    float m=ws[SO_G1+tid]*(1.0f/4096.0f);
    float v=ws[SO_G1Q+tid]*(1.0f/4096.0f)-m*m; if(v<0)v=0;
    mi[tid][0]=m; mi[tid][1]=rsqrtf(v+EPSB);
  }
  __syncthreads();
  int e=blockIdx.x*256+tid;
  float acc[16];
  #pragma unroll
  for(int k=0;k<16;k++) acc[k]=0;
  for(int o=0;o<64;o++){
    float z=ws[F_Z1EC+(size_t)e*64+o];
    float h=(z-mi[o][0])*mi[o][1];
    h=h>0?h:0;
    #pragma unroll
    for(int k=0;k<16;k++) acc[k]+=w2s[k*64+o]*h;
  }
  float s[16], q[16];
  #pragma unroll
  for(int k=0;k<16;k++){
    ws[F_FCB+(size_t)e*16+k]=acc[k];
    s[k]=acc[k]; q[k]=acc[k]*acc[k];
  }
  red32_atomic(ws, SO_G2, SO_G2Q, s, q);
}

// ---------------- edge_feature fill [4,1025,16] ----------------
__global__ __launch_bounds__(256) void k_ef2(float* __restrict__ ws){
  int t=blockIdx.x*256+threadIdx.x;
  if(t>=4*1025*16) return;
  int h=t&15, r=t>>4;
  int b=r/1025, pos=r%1025;
  float v=0;
  if(pos<1024){
    int e=b*1024+pos;
    float z=ws[F_FCB+(size_t)e*16+h];
    float m=ws[SO_G2+h]*(1.0f/4096.0f);
    float va=ws[SO_G2Q+h]*(1.0f/4096.0f)-m*m; if(va<0)va=0;
    v=(z-m)*rsqrtf(va+EPSB);
    v=v>0?v:0;
  }
  ws[F_EDGEF+t]=v;
}

// ---------------- main per-pair kernel: interior output ----------------
__global__ __launch_bounds__(256) void k_pair(const float* __restrict__ ab,
    const int* __restrict__ sd, const float* __restrict__ ang, const float* __restrict__ cen,
    const int* __restrict__ ep, const float* __restrict__ sdemb, const float* __restrict__ edisw,
    const float* __restrict__ angW1, const float* __restrict__ angW2,
    const float* __restrict__ cenW1, const float* __restrict__ cenW2,
    const float* __restrict__ ws, float* __restrict__ out){
  __shared__ float wd[1280];
  __shared__ float w2a[256], w2c[256];
  __shared__ float Aa[16], Ac[16], m2a[16], i2a[16], m2c[16], i2c[16];
  __shared__ float muA, muC, varA, varC;
  int tid=threadIdx.x;
  for(int i=tid;i<1280;i+=256) wd[i]=edisw[i];
  w2a[tid]=angW2[tid]; w2c[tid]=cenW2[tid];
  if(tid==0){
    float s=ws[SO_ANGX], q=ws[SO_ANGX+1];
    float mu=s*(1.0f/262144.0f);
    float v=q*(1.0f/262144.0f)-mu*mu; if(v<0)v=0;
    muA=mu; varA=v;
    s=ws[SO_CENX]; q=ws[SO_CENX+1];
    mu=s*(1.0f/262144.0f);
    v=q*(1.0f/262144.0f)-mu*mu; if(v<0)v=0;
    muC=mu; varC=v;
  }
  __syncthreads();
  if(tid<16){
    float w=angW1[tid]; Aa[tid]=w/sqrtf(varA*w*w+EPSB);
    float m=ws[SO_ANG2+tid]*(1.0f/262144.0f);
    float v=ws[SO_ANG2Q+tid]*(1.0f/262144.0f)-m*m; if(v<0)v=0;
    m2a[tid]=m; i2a[tid]=rsqrtf(v+EPSB);
  } else if(tid<32){
    int h=tid-16;
    float w=cenW1[h]; Ac[h]=w/sqrtf(varC*w*w+EPSB);
    float m=ws[SO_CEN2+h]*(1.0f/262144.0f);
    float v=ws[SO_CEN2Q+h]*(1.0f/262144.0f)-m*m; if(v<0)v=0;
    m2c[h]=m; i2c[h]=rsqrtf(v+EPSB);
  }
  __syncthreads();
  int t=blockIdx.x*256+tid;            // b,i,j
  int b=t>>16, rem=t&65535, i=rem>>8, j=rem&255;
  int sdv=sd[t];
  float xa=ang[t], xc0=cen[t];
  float acc[16];
  const float* se=sdemb+(size_t)sdv*16;
  #pragma unroll
  for(int k=0;k<16;k++) acc[k]=se[k];
  { // angle MLP
    float xc=xa-muA;
    float h1[16];
    #pragma unroll
    for(int h=0;h<16;h++){ float v=xc*Aa[h]; h1[h]=v>0?v:0; }
    #pragma unroll
    for(int k=0;k<16;k++){
      float z=0;
      #pragma unroll
      for(int h=0;h<16;h++) z+=w2a[k*16+h]*h1[h];
      float r=(z-m2a[k])*i2a[k];
      acc[k]+= r>0?r:0;
    }
  }
  { // centroid MLP
    float xc=xc0-muC;
    float h1[16];
    #pragma unroll
    for(int h=0;h<16;h++){ float v=xc*Ac[h]; h1[h]=v>0?v:0; }
    #pragma unroll
    for(int k=0;k<16;k++){
      float z=0;
      #pragma unroll
      for(int h=0;h<16;h++) z+=w2c[k*16+h]*h1[h];
      float r=(z-m2c[k])*i2c[k];
      acc[k]+= r>0?r:0;
    }
  }
  { // multi-hop edge bias
    int sdm = sdv==0 ? 1 : sdv;
    if(sdm>1) sdm-=1;
    if(sdm>5) sdm=5;
    float inv=1.0f/((float)sdm+1e-6f);
    float eb[16];
    #pragma unroll
    for(int k=0;k<16;k++) eb[k]=0;
    const float* EF=ws+F_EDGEF+(size_t)b*1025*16;
    #pragma unroll
    for(int d=0;d<5;d++){
      int idx=ep[(size_t)t*5+d];
      const float* r=EF+(size_t)idx*16;
      float e16[16];
      #pragma unroll
      for(int k=0;k<16;k+=4){
        float4 v=*(const float4*)(r+k);
        e16[k]=v.x; e16[k+1]=v.y; e16[k+2]=v.z; e16[k+3]=v.w;
      }
      const float* wdd=wd+d*256;
      #pragma unroll
      for(int h=0;h<16;h++){
        float evv=e16[h];
        #pragma unroll
        for(int k=0;k<16;k++) eb[k]+=evv*wdd[h*16+k];
      }
    }
    #pragma unroll
    for(int k=0;k<16;k++) acc[k]+=eb[k]*inv;
  }
  float base2=2.0f*ab[(size_t)b*66049+(size_t)(i+1)*257+(j+1)];
  #pragma unroll
  for(int k=0;k<16;k++)
    out[(((size_t)b*16+k)*257+(i+1))*257+(j+1)]=acc[k]+base2;
}

// ---------------- borders: row 0 and col 0 ----------------
__global__ __launch_bounds__(256) void k_border(const float* __restrict__ ab,
    const float* __restrict__ virt, float* __restrict__ out){
  int t=blockIdx.x*256+threadIdx.x;
  if(t>=4*16*513) return;
  int idx=t%513, bh=t/513;
  int b=bh>>4, h=bh&15;
  float v=virt[h];
  if(idx<257){
    out[(((size_t)b*16+h)*257)*257+idx]=2.0f*ab[(size_t)b*66049+idx]+v;
  } else {
    int p=idx-256;   // 1..256
    out[(((size_t)b*16+h)*257+p)*257]=2.0f*ab[(size_t)b*66049+(size_t)p*257]+v;
  }
}

extern "C" void kernel_launch(void* const* d_in, const int* in_sizes, int n_in,
                              void* d_out, int out_size, void* d_ws, size_t ws_size,
                              hipStream_t stream) {
  const float* ab    =(const float*)d_in[0];
  const int*   sdist =(const int*)  d_in[1];
  const float* ang   =(const float*)d_in[2];
  const float* cen   =(const float*)d_in[3];
  const int*   ep    =(const int*)  d_in[4];
  const float* edata =(const float*)d_in[5];
  const float* etype =(const float*)d_in[6];
  const float* elen  =(const float*)d_in[7];
  const float* econv =(const float*)d_in[8];
  const int*   src   =(const int*)  d_in[10];
  const int*   dst   =(const int*)  d_in[11];
  const float* nf    =(const float*)d_in[12];
  const float* sdemb =(const float*)d_in[13];
  const float* virt  =(const float*)d_in[14];
  const float* angW1 =(const float*)d_in[15];
  const float* angW2 =(const float*)d_in[16];
  const float* cenW1 =(const float*)d_in[17];
  const float* cenW2 =(const float*)d_in[18];
  const float* etW1  =(const float*)d_in[19];
  const float* etW2  =(const float*)d_in[20];
  const float* elW1  =(const float*)d_in[21];
  const float* elW2  =(const float*)d_in[22];
  const float* evW1  =(const float*)d_in[23];
  const float* evW2  =(const float*)d_in[24];
  const float* c1w   =(const float*)d_in[25];
  const float* c2w   =(const float*)d_in[26];
  const float* c3w   =(const float*)d_in[27];
  const float* fcw   =(const float*)d_in[28];
  const float* edisw =(const float*)d_in[29];
  const float* ecWp  =(const float*)d_in[30];
  const float* ecW1  =(const float*)d_in[31];
  const float* ecW2  =(const float*)d_in[32];
  float* ws=(float*)d_ws;
  float* out=(float*)d_out;

  hipMemsetAsync(d_ws, 0, STATS_FLOATS*sizeof(float), stream);

  k_wprep<<<480,256,0,stream>>>(c2w,c3w,(ushort*)(ws+F_WT2),(ushort*)(ws+F_WT3));

  k_scalar_stats<<<256,256,0,stream>>>(ang,cen,ws);
  k_ac_l2stats<<<128,256,0,stream>>>(ang,angW1,angW2,ws,SO_ANGX,SO_ANG2,SO_ANG2Q);
  k_ac_l2stats<<<128,256,0,stream>>>(cen,cenW1,cenW2,ws,SO_CENX,SO_CEN2,SO_CEN2Q);

  k_conv1<<<512,64,0,stream>>>(edata,c1w,ws);
  k_convmf<64,128,8><<<512,256,0,stream>>>(ws+F_Y13,(const ushort*)(ws+F_WT2),ws+F_Y2,ws,
                                           SO_C1,SO_C1Q,SO_C2,SO_C2Q);
  k_convmf<128,256,4><<<1024,256,0,stream>>>(ws+F_Y2,(const ushort*)(ws+F_WT3),ws+F_Y13,ws,
                                             SO_C2,SO_C2Q,SO_C3,SO_C3Q);
  k_pool<<<4096,256,0,stream>>>(ws);
  k_fc<<<256,256,0,stream>>>(fcw,ws);

  k_small_l1<11><<<16,256,0,stream>>>(etype,etW1,ws,SO_ET1,SO_ET1Q);
  k_small_l1<1> <<<16,256,0,stream>>>(elen ,elW1,ws,SO_EL1,SO_EL1Q);
  k_small_l1<3> <<<16,256,0,stream>>>(econv,evW1,ws,SO_EV1,SO_EV1Q);
  k_small_l2<11><<<16,256,0,stream>>>(etype,etW1,etW2,ws,SO_ET1,SO_ET1Q,SO_ET2,SO_ET2Q);
  k_small_l2<1> <<<16,256,0,stream>>>(elen ,elW1,elW2,ws,SO_EL1,SO_EL1Q,SO_EL2,SO_EL2Q);
  k_small_l2<3> <<<16,256,0,stream>>>(econv,evW1,evW2,ws,SO_EV1,SO_EV1Q,SO_EV2,SO_EV2Q);

  k_ef<<<16,256,0,stream>>>(etype,etW1,etW2,elen,elW1,elW2,econv,evW1,evW2,ws);
  k_proj<<<64,256,0,stream>>>(nf,ecWp,ws);
  k_agg<<<16,256,0,stream>>>(src,dst,ecW1,ws);
  k_ec2<<<16,256,0,stream>>>(ecW2,ws);
  k_ef2<<<257,256,0,stream>>>(ws);

  k_pair<<<1024,256,0,stream>>>(ab,sdist,ang,cen,ep,sdemb,edisw,angW1,angW2,cenW1,cenW2,ws,out);
  k_border<<<129,256,0,stream>>>(ab,virt,out);
}

// Round 4
// 386.975 us; speedup vs baseline: 2.1706x; 1.0464x over previous
//
#include <hip/hip_runtime.h>

#define EPSB 1e-5f
#define B_ 4
#define N_ 256
#define H_ 16
#define D_ 5
#define E_ 4096
#define M_PAIR (B_*N_*N_)   // 262144

typedef __attribute__((ext_vector_type(8))) short short8;
typedef __attribute__((ext_vector_type(4))) float f32x4;

// ---- stats slot offsets (floats) in ws ----
enum {
  SO_ANGX = 0,               // ang sum, ang sq, cen sum, cen sq
  SO_CENX = 2,
  SO_ANG2 = 16,  SO_ANG2Q = 32,
  SO_CEN2 = 48,  SO_CEN2Q = 64,
  SO_C1   = 96,  SO_C1Q   = 160,
  SO_C2   = 224, SO_C2Q   = 352,
  SO_C3   = 480, SO_C3Q   = 736,
  SO_FC   = 992, SO_FCQ   = 1008,
  SO_ET1  = 1024, SO_ET1Q = 1040, SO_ET2 = 1056, SO_ET2Q = 1072,
  SO_EL1  = 1088, SO_EL1Q = 1104, SO_EL2 = 1120, SO_EL2Q = 1136,
  SO_EV1  = 1152, SO_EV1Q = 1168, SO_EV2 = 1184, SO_EV2Q = 1200,
  SO_G1   = 1216, SO_G1Q  = 1280,
  SO_G2   = 1344, SO_G2Q  = 1360,
  STATS_FLOATS = 2048
};

// ---- buffer offsets (floats) ----
// y1: [E][20][64] fp32 (then aliased by y3 [E][20][256])
static constexpr size_t F_Y13  = 2048;
static constexpr size_t F_Y2   = F_Y13 + 20971520;     // [E][20][128] fp32
static constexpr size_t F_POOL = F_Y2 + 10485760;      // E*256
static constexpr size_t F_FCB  = F_POOL + 1048576;     // E*16 (fc out, later z2 of edgeconv)
static constexpr size_t F_EF   = F_FCB + 65536;        // E*16
static constexpr size_t F_PROJ = F_EF + 65536;         // 1024*16
static constexpr size_t F_Z1EC = F_PROJ + 16384;       // E*64
static constexpr size_t F_EDGEF= F_Z1EC + 262144;      // 4*1025*16
static constexpr size_t F_WT2  = F_EDGEF + 65600;      // 128*192 bf16 = 12288 floats
static constexpr size_t F_WT3  = F_WT2 + 12288;        // 256*384 bf16 = 49152 floats

__device__ __forceinline__ float waveSum(float v){
  #pragma unroll
  for(int o=32;o;o>>=1) v += __shfl_down(v,o);
  return v;
}

__device__ __forceinline__ ushort f2bf(float f){
  uint u = __float_as_uint(f);
  uint r = (u + 0x7FFF + ((u>>16)&1)) >> 16;
  return (ushort)r;
}

// block = 256 threads (4 waves). Reduce 16 sums + 16 sumsqs, atomicAdd to ws.
__device__ __forceinline__ void red32_atomic(float* ws, int so, int soq, float* s, float* q){
  __shared__ float red[4][32];
  int tid=threadIdx.x, lane=tid&63, wid=tid>>6;
  #pragma unroll
  for(int k=0;k<16;k++){
    float rs=waveSum(s[k]), rq=waveSum(q[k]);
    if(lane==0){ red[wid][k]=rs; red[wid][16+k]=rq; }
  }
  __syncthreads();
  if(tid<32){
    float t=red[0][tid]+red[1][tid]+red[2][tid]+red[3][tid];
    atomicAdd(&ws[tid<16 ? so+tid : soq+(tid-16)], t);
  }
}

// ---------------- scalar stats of angle & centroid ----------------
__global__ __launch_bounds__(256) void k_scalar_stats(const float* __restrict__ ang,
    const float* __restrict__ cen, float* __restrict__ st){
  int tid = blockIdx.x*256 + threadIdx.x;
  float sa=0, qa=0, sc=0, qc=0;
  for(int i=tid; i<M_PAIR; i += gridDim.x*256){
    float a=ang[i], c=cen[i];
    sa+=a; qa+=a*a; sc+=c; qc+=c*c;
  }
  __shared__ float red[4][4];
  int lane=threadIdx.x&63, wid=threadIdx.x>>6;
  sa=waveSum(sa); qa=waveSum(qa); sc=waveSum(sc); qc=waveSum(qc);
  if(lane==0){ red[wid][0]=sa; red[wid][1]=qa; red[wid][2]=sc; red[wid][3]=qc; }
  __syncthreads();
  if(threadIdx.x<4){
    float t=red[0][threadIdx.x]+red[1][threadIdx.x]+red[2][threadIdx.x]+red[3][threadIdx.x];
    atomicAdd(&st[threadIdx.x], t);
  }
}

// ---------------- layer-2 stats for angle/cent MLPs ----------------
__global__ __launch_bounds__(256) void k_ac_l2stats(const float* __restrict__ x,
    const float* __restrict__ W1, const float* __restrict__ W2,
    float* __restrict__ st, int soX, int soS, int soQ){
  __shared__ float w2s[256];
  __shared__ float Ah[16];
  __shared__ float mu_s, var_s;
  int tid=threadIdx.x;
  w2s[tid]=W2[tid];
  if(tid==0){
    float s=st[soX], qq=st[soX+1];
    float mu=s*(1.0f/262144.0f);
    float v=qq*(1.0f/262144.0f)-mu*mu; if(v<0)v=0;
    mu_s=mu; var_s=v;
  }
  __syncthreads();
  if(tid<16){ float w=W1[tid]; Ah[tid]=w/sqrtf(var_s*w*w+EPSB); }
  __syncthreads();
  float s[16], q[16];
  #pragma unroll
  for(int k=0;k<16;k++){ s[k]=0; q[k]=0; }
  for(int i=blockIdx.x*256+tid; i<M_PAIR; i+=gridDim.x*256){
    float xc=x[i]-mu_s;
    float h1[16];
    #pragma unroll
    for(int h=0;h<16;h++){ float t=xc*Ah[h]; h1[h]=t>0?t:0; }
    #pragma unroll
    for(int k=0;k<16;k++){
      float z=0;
      #pragma unroll
      for(int h=0;h<16;h++) z+=w2s[k*16+h]*h1[h];
      s[k]+=z; q[k]+=z*z;
    }
  }
  red32_atomic(st, soS, soQ, s, q);
}

// -------- weight prep: pack conv weights to MFMA-fragment order --------
// wt[ct][ks][lane(64)][8]  with o = ct*16 + (lane&15), k = ks*32 + (lane>>4)*8 + j
__global__ __launch_bounds__(256) void k_wprep(const float* __restrict__ c2w,
    const float* __restrict__ c3w, ushort* __restrict__ wt2, ushort* __restrict__ wt3){
  int t = blockIdx.x*256 + threadIdx.x;
  if(t < 128*192){
    int idx=t;
    int j=idx&7, lane=(idx>>3)&63, ks=(idx>>9)%6, ct=idx/3072;
    int l16=lane&15, lhi=lane>>4;
    int o=ct*16+l16, tap=ks/2, c=(ks%2)*32+lhi*8+j;
    wt2[idx]=f2bf(c2w[(o*64+c)*3+tap]);
  } else {
    int idx=t-128*192;
    if(idx<256*384){
      int j=idx&7, lane=(idx>>3)&63, ks=(idx>>9)%12, ct=idx/6144;
      int l16=lane&15, lhi=lane>>4;
      int o=ct*16+l16, tap=ks/4, c=(ks%4)*32+lhi*8+j;
      wt3[idx]=f2bf(c3w[(o*128+c)*3+tap]);
    }
  }
}

// ---------------- conv1: [E,12,20] -> y1 [E][20][64] + stats ----------------
// block = 256 thr (4 waves), 16 edges/block; wave eg handles edges eg*4..eg*4+3
__global__ __launch_bounds__(256) void k_conv1(const float* __restrict__ ed,
    const float* __restrict__ w, float* __restrict__ ws){
  __shared__ float wsh[64*36];
  __shared__ float xs[16][12][20];
  __shared__ float reds[4][64], redq[4][64];
  int tid=threadIdx.x;
  for(int i=tid;i<64*36;i+=256) wsh[i]=w[i];
  int e0=blockIdx.x*16;
  for(int i=tid;i<16*240;i+=256){
    int e=i/240, r=i%240, l=r/12, c=r%12;
    xs[e][c][l]=ed[(size_t)(e0+e)*240+r];
  }
  __syncthreads();
  int o=tid&63, eg=tid>>6;
  float* y1=ws+F_Y13;
  float ssum=0, ssq=0;
  for(int ee=0;ee<4;ee++){
    int e=eg*4+ee;
    float acc[20];
    #pragma unroll
    for(int l=0;l<20;l++) acc[l]=0;
    for(int c=0;c<12;c++){
      float w0=wsh[o*36+c*3], w1=wsh[o*36+c*3+1], w2=wsh[o*36+c*3+2];
      const float* xr=xs[e][c];
      #pragma unroll
      for(int l=0;l<20;l++){
        acc[l]=fmaf(w1,xr[l],acc[l]);
        if(l>0)  acc[l]=fmaf(w0,xr[l-1],acc[l]);
        if(l<19) acc[l]=fmaf(w2,xr[l+1],acc[l]);
      }
    }
    size_t base=((size_t)(e0+e)*20)*64;
    #pragma unroll
    for(int l=0;l<20;l++){ y1[base+(size_t)l*64+o]=acc[l]; ssum+=acc[l]; ssq+=acc[l]*acc[l]; }
  }
  reds[eg][o]=ssum; redq[eg][o]=ssq;
  __syncthreads();
  if(tid<64){
    float s=reds[0][tid]+reds[1][tid]+reds[2][tid]+reds[3][tid];
    atomicAdd(&ws[SO_C1+tid], s);
  } else if(tid<128){
    int oo=tid-64;
    float q=redq[0][oo]+redq[1][oo]+redq[2][oo]+redq[3][oo];
    atomicAdd(&ws[SO_C1Q+oo], q);
  }
}

// ---------------- MFMA conv (conv2/conv3): bn+lrelu(yin) conv w -> yout + stats ----
// yin: [E][20][CIN] fp32.  wt: packed bf16 (k_wprep layout).  yout: [E][20][OUT] fp32.
// Block: 256 thr (4 waves), EPB edges -> M = EPB*20 rows, N = OUT cols, K = 3*CIN.
template<int CIN, int OUT, int EPB>
__global__ __launch_bounds__(256) void k_convmf(
    const float* __restrict__ yin, const ushort* __restrict__ wt,
    float* __restrict__ yout, float* __restrict__ ws,
    int soIn, int soInQ, int soOut, int soOutQ)
{
  constexpr int K = CIN*3;
  constexpr int KSTEPS = K/32;
  constexpr int M = EPB*20;
  constexpr int ROWT = M/16;
  constexpr int WCOLT = OUT/64;            // col-tiles per wave (4 waves)
  constexpr int ROWS = EPB*22;             // zero-padded length dim
  constexpr int RB = CIN*2;                // row bytes in LDS
  constexpr uint SWZ = RB/16 - 1;          // full-row slot swizzle mask
  __shared__ ushort xs[ROWS*CIN];
  __shared__ float mi[CIN][2];
  int tid = threadIdx.x;
  for(int c=tid; c<CIN; c+=256){
    float m=ws[soIn+c]*(1.0f/81920.0f);
    float v=ws[soInQ+c]*(1.0f/81920.0f)-m*m; if(v<0)v=0;
    mi[c][0]=m; mi[c][1]=rsqrtf(v+EPSB);
  }
  // zero pad rows lp=0,21 (swizzle permutes within-row; zero fill can stay linear)
  uint* xs32 = (uint*)xs;
  for(int i=tid; i<EPB*2*(CIN/2); i+=256){
    int e=i/(CIN), r=i%(CIN); int lp = (r < CIN/2)? 0:21; int cw = r%(CIN/2);
    xs32[(e*22+lp)*(CIN/2)+cw]=0;
  }
  __syncthreads();
  // stage: read yin, bn+lrelu, bf16, swizzled LDS write
  int e0 = blockIdx.x*EPB;
  const float* src = yin + (size_t)e0*20*CIN;
  for(int i=tid; i<EPB*20*(CIN/4); i+=256){
    int c4 = i%(CIN/4); int rl = i/(CIN/4);      // rl = e*20+l
    int c = c4*4;
    float4 v = *(const float4*)(src + (size_t)rl*CIN + c);
    float f0=(v.x-mi[c  ][0])*mi[c  ][1]; f0= f0>=0?f0:0.01f*f0;
    float f1=(v.y-mi[c+1][0])*mi[c+1][1]; f1= f1>=0?f1:0.01f*f1;
    float f2=(v.z-mi[c+2][0])*mi[c+2][1]; f2= f2>=0?f2:0.01f*f2;
    float f3=(v.w-mi[c+3][0])*mi[c+3][1]; f3= f3>=0?f3:0.01f*f3;
    int e = rl/20, l=rl%20;
    int row = e*22 + l + 1;
    uint byteoff = (uint)row*RB + (((uint)c*2) ^ (uint)((row&SWZ)<<4));
    uint pk0 = (uint)f2bf(f0) | ((uint)f2bf(f1)<<16);
    uint pk1 = (uint)f2bf(f2) | ((uint)f2bf(f3)<<16);
    *(uint2*)((char*)xs + byteoff) = make_uint2(pk0,pk1);
  }
  __syncthreads();

  int lane = tid&63, wid = tid>>6;
  int l16 = lane&15, lhi = lane>>4;
  int colbase = wid*(OUT/4);
  f32x4 acc[ROWT][WCOLT];
  #pragma unroll
  for(int m=0;m<ROWT;m++)
    #pragma unroll
    for(int n=0;n<WCOLT;n++) acc[m][n]=(f32x4){0,0,0,0};
  int rowc[ROWT];
  #pragma unroll
  for(int m=0;m<ROWT;m++){ int r=m*16+l16; rowc[m]=(r/20)*22 + (r%20); }
  const ushort* wptile[WCOLT];
  #pragma unroll
  for(int n=0;n<WCOLT;n++)
    wptile[n] = wt + ((size_t)(wid*WCOLT + n)*KSTEPS)*512 + (size_t)lane*8;

  short8 aF0[ROWT], bF0[WCOLT], aF1[ROWT], bF1[WCOLT];

#define LOADK(ksv, A, B) { \
    int t_=(ksv)/(CIN/32); int c0_=((ksv)%(CIN/32))*32 + lhi*8; \
    _Pragma("unroll") \
    for(int m=0;m<ROWT;m++){ \
      int row_=rowc[m]+t_; \
      uint off_=(uint)row_*RB + (((uint)c0_*2) ^ (uint)((row_&SWZ)<<4)); \
      A[m]=*(const short8*)((char*)xs+off_); } \
    _Pragma("unroll") \
    for(int n=0;n<WCOLT;n++) B[n]=*(const short8*)(wptile[n]+(ksv)*512); }

#define MFMAK(A, B) { \
    _Pragma("unroll") \
    for(int m=0;m<ROWT;m++) \
      _Pragma("unroll") \
      for(int n=0;n<WCOLT;n++) \
        acc[m][n]=__builtin_amdgcn_mfma_f32_16x16x32_bf16(A[m],B[n],acc[m][n],0,0,0); }

  LOADK(0, aF0, bF0);
  #pragma unroll
  for(int kp=0; kp<KSTEPS/2; kp++){
    int ks = kp*2;
    LOADK(ks+1, aF1, bF1);
    MFMAK(aF0, bF0);
    if(ks+2<KSTEPS) LOADK(ks+2, aF0, bF0);
    MFMAK(aF1, bF1);
  }
#undef LOADK
#undef MFMAK

  // per-output-channel stats
  #pragma unroll
  for(int n=0;n<WCOLT;n++){
    float s=0,q=0;
    #pragma unroll
    for(int m=0;m<ROWT;m++)
      #pragma unroll
      for(int j=0;j<4;j++){ float a=acc[m][n][j]; s+=a; q+=a*a; }
    s += __shfl_xor(s,16); s += __shfl_xor(s,32);
    q += __shfl_xor(q,16); q += __shfl_xor(q,32);
    if(lhi==0){
      int o = colbase+n*16+l16;
      atomicAdd(&ws[soOut+o], s);
      atomicAdd(&ws[soOutQ+o], q);
    }
  }
  // store yout [R][OUT], R global = blockIdx*M + m*16 + lhi*4 + j
  float* dst = yout + (size_t)blockIdx.x*M*OUT;
  #pragma unroll
  for(int m=0;m<ROWT;m++)
    #pragma unroll
    for(int j=0;j<4;j++){
      int R = m*16 + lhi*4 + j;
      #pragma unroll
      for(int n=0;n<WCOLT;n++)
        dst[(size_t)R*OUT + colbase + n*16 + l16] = acc[m][n][j];
    }
}

// ---------------- pool: mean_l lrelu(bn(y3)) -> pooled [E,256] ----------------
// y3 layout [E][20][256]
__global__ __launch_bounds__(256) void k_pool(float* __restrict__ ws){
  int t=blockIdx.x*256+threadIdx.x;   // e*256+o
  int o=t&255, e=t>>8;
  float m=ws[SO_C3+o]*(1.0f/81920.0f);
  float v=ws[SO_C3Q+o]*(1.0f/81920.0f)-m*m; if(v<0)v=0;
  float inv=rsqrtf(v+EPSB);
  const float* y3=ws+F_Y13+(size_t)e*20*256+o;
  float s=0;
  #pragma unroll
  for(int l=0;l<20;l++){
    float x=(y3[(size_t)l*256]-m)*inv;
    s += x>=0.f? x : 0.01f*x;
  }
  ws[F_POOL+t]=s*(1.0f/20.0f);
}

// ---------------- fc: pooled @ curv_fc.T -> fcb [E,16] + stats ----------------
__global__ __launch_bounds__(256) void k_fc(const float* __restrict__ fcw, float* __restrict__ ws){
  __shared__ float ps[16][260];
  __shared__ float red[4][32];
  int tid=threadIdx.x;
  int e0=blockIdx.x*16;
  for(int i=tid;i<4096;i+=256){
    ps[i>>8][i&255]=ws[F_POOL+(size_t)(e0+(i>>8))*256+(i&255)];
  }
  __syncthreads();
  int e=tid>>4, h=tid&15;
  const float* wr=fcw+(size_t)h*256;
  float z=0;
  for(int c=0;c<256;c++) z+=ps[e][c]*wr[c];
  ws[F_FCB+(size_t)(e0+e)*16+h]=z;
  float s=z, q=z*z;
  #pragma unroll
  for(int o=16;o<64;o<<=1){ s+=__shfl_down(s,o); q+=__shfl_down(q,o); }
  int lane=tid&63, wid=tid>>6;
  if(lane<16){ red[wid][lane]=s; red[wid][16+lane]=q; }
  __syncthreads();
  if(tid<32){
    float v=red[0][tid]+red[1][tid]+red[2][tid]+red[3][tid];
    atomicAdd(&ws[tid<16? SO_FC+tid : SO_FCQ+(tid-16)], v);
  }
}

// ---------------- small-MLP layer-1 stats ----------------
template<int DIM>
__global__ __launch_bounds__(256) void k_small_l1(const float* __restrict__ x,
    const float* __restrict__ W1, float* __restrict__ ws, int so, int soq){
  __shared__ float w1s[16*DIM];
  int tid=threadIdx.x;
  if(tid<16*DIM) w1s[tid]=W1[tid];
  __syncthreads();
  int e=blockIdx.x*256+tid;
  float xv[DIM];
  #pragma unroll
  for(int j=0;j<DIM;j++) xv[j]=x[(size_t)e*DIM+j];
  float s[16], q[16];
  #pragma unroll
  for(int k=0;k<16;k++){
    float z=0;
    #pragma unroll
    for(int j=0;j<DIM;j++) z+=w1s[k*DIM+j]*xv[j];
    s[k]=z; q[k]=z*z;
  }
  red32_atomic(ws, so, soq, s, q);
}

// ---------------- small-MLP layer-2 stats ----------------
template<int DIM>
__global__ __launch_bounds__(256) void k_small_l2(const float* __restrict__ x,
    const float* __restrict__ W1, const float* __restrict__ W2, float* __restrict__ ws,
    int so1, int so1q, int so2, int so2q){
  __shared__ float w1s[16*DIM];
  __shared__ float w2s[256];
  __shared__ float mi[16][2];
  int tid=threadIdx.x;
  if(tid<16*DIM) w1s[tid]=W1[tid];
  w2s[tid]=W2[tid];
  if(tid<16){
    float m=ws[so1+tid]*(1.0f/4096.0f);
    float v=ws[so1q+tid]*(1.0f/4096.0f)-m*m; if(v<0)v=0;
    mi[tid][0]=m; mi[tid][1]=rsqrtf(v+EPSB);
  }
  __syncthreads();
  int e=blockIdx.x*256+tid;
  float xv[DIM];
  #pragma unroll
  for(int j=0;j<DIM;j++) xv[j]=x[(size_t)e*DIM+j];
  float h1[16];
  #pragma unroll
  for(int h=0;h<16;h++){
    float z=0;
    #pragma unroll
    for(int j=0;j<DIM;j++) z+=w1s[h*DIM+j]*xv[j];
    z=(z-mi[h][0])*mi[h][1];
    h1[h]=z>0?z:0;
  }
  float s[16], q[16];
  #pragma unroll
  for(int k=0;k<16;k++){
    float z=0;
    #pragma unroll
    for(int h=0;h<16;h++) z+=w2s[k*16+h]*h1[h];
    s[k]=z; q[k]=z*z;
  }
  red32_atomic(ws, so2, so2q, s, q);
}

// ---------------- ef assembly: fc-bn + 3 small MLPs -> ef [E,16] ----------------
__device__ __constant__ int EF_BASES[7][2] = {
  {SO_ET1,SO_ET1Q},{SO_ET2,SO_ET2Q},{SO_EL1,SO_EL1Q},{SO_EL2,SO_EL2Q},
  {SO_EV1,SO_EV1Q},{SO_EV2,SO_EV2Q},{SO_FC,SO_FCQ}
};

__global__ __launch_bounds__(256) void k_ef(
    const float* __restrict__ et, const float* __restrict__ etW1, const float* __restrict__ etW2,
    const float* __restrict__ el, const float* __restrict__ elW1, const float* __restrict__ elW2,
    const float* __restrict__ ev, const float* __restrict__ evW1, const float* __restrict__ evW2,
    float* __restrict__ ws){
  __shared__ float w1et[176], w1el[16], w1ev[48];
  __shared__ float w2et[256], w2el[256], w2ev[256];
  __shared__ float mi[7][16][2];
  int tid=threadIdx.x;
  if(tid<176) w1et[tid]=etW1[tid];
  if(tid<16)  w1el[tid]=elW1[tid];
  if(tid<48)  w1ev[tid]=evW1[tid];
  w2et[tid]=etW2[tid]; w2el[tid]=elW2[tid]; w2ev[tid]=evW2[tid];
  if(tid<112){
    int g=tid>>4, h=tid&15;
    float m=ws[EF_BASES[g][0]+h]*(1.0f/4096.0f);
    float v=ws[EF_BASES[g][1]+h]*(1.0f/4096.0f)-m*m; if(v<0)v=0;
    mi[g][h][0]=m; mi[g][h][1]=rsqrtf(v+EPSB);
  }
  __syncthreads();
  int e=blockIdx.x*256+tid;
  float acc[16];
  #pragma unroll
  for(int h=0;h<16;h++){
    float z=ws[F_FCB+(size_t)e*16+h];
    acc[h]=(z-mi[6][h][0])*mi[6][h][1];   // fc: BN, no relu
  }
  { // etype (dim 11)
    float xv[11];
    #pragma unroll
    for(int j=0;j<11;j++) xv[j]=et[(size_t)e*11+j];
    float h1[16];
    #pragma unroll
    for(int h=0;h<16;h++){
      float z=0;
      #pragma unroll
      for(int j=0;j<11;j++) z+=w1et[h*11+j]*xv[j];
      z=(z-mi[0][h][0])*mi[0][h][1];
      h1[h]=z>0?z:0;
    }
    #pragma unroll
    for(int k=0;k<16;k++){
      float z=0;
      #pragma unroll
      for(int h=0;h<16;h++) z+=w2et[k*16+h]*h1[h];
      z=(z-mi[1][k][0])*mi[1][k][1];
      acc[k]+= z>0?z:0;
    }
  }
  { // elen (dim 1)
    float x=el[e];
    float h1[16];
    #pragma unroll
    for(int h=0;h<16;h++){
      float z=x*w1el[h];
      z=(z-mi[2][h][0])*mi[2][h][1];
      h1[h]=z>0?z:0;
    }
    #pragma unroll
    for(int k=0;k<16;k++){
      float z=0;
      #pragma unroll
      for(int h=0;h<16;h++) z+=w2el[k*16+h]*h1[h];
      z=(z-mi[3][k][0])*mi[3][k][1];
      acc[k]+= z>0?z:0;
    }
  }
  { // econv (dim 3)
    float xv[3];
    #pragma unroll
    for(int j=0;j<3;j++) xv[j]=ev[(size_t)e*3+j];
    float h1[16];
    #pragma unroll
    for(int h=0;h<16;h++){
      float z=0;
      #pragma unroll
      for(int j=0;j<3;j++) z+=w1ev[h*3+j]*xv[j];
      z=(z-mi[4][h][0])*mi[4][h][1];
      h1[h]=z>0?z:0;
    }
    #pragma unroll
    for(int k=0;k<16;k++){
      float z=0;
      #pragma unroll
      for(int h=0;h<16;h++) z+=w2ev[k*16+h]*h1[h];
      z=(z-mi[5][k][0])*mi[5][k][1];
      acc[k]+= z>0?z:0;
    }
  }
  #pragma unroll
  for(int h=0;h<16;h++) ws[F_EF+(size_t)e*16+h]=acc[h];
}

// ---------------- proj: node_feat @ ec_Wp.T -> proj [1024,16] ----------------
__global__ __launch_bounds__(256) void k_proj(const float* __restrict__ nf,
    const float* __restrict__ Wp, float* __restrict__ ws){
  __shared__ float wps[4096];
  int tid=threadIdx.x;
  for(int i=tid;i<4096;i+=256) wps[i]=Wp[i];
  __syncthreads();
  int t=blockIdx.x*256+tid;
  int v=t>>4, h=t&15;
  const float* row=nf+(size_t)v*256;
  const float* wr=wps+h*256;
  float z=0;
  for(int c=0;c<256;c++) z+=row[c]*wr[c];
  ws[F_PROJ+t]=z;
}

// ---------------- agg + edgeconv layer1 -> z1ec [E,64] + stats ----------------
__global__ __launch_bounds__(256) void k_agg(const int* __restrict__ src, const int* __restrict__ dst,
    const float* __restrict__ ecW1, float* __restrict__ ws){
  __shared__ float w1s[1024];
  int tid=threadIdx.x;
  for(int i=tid;i<1024;i+=256) w1s[i]=ecW1[i];
  __syncthreads();
  int e=blockIdx.x*256+tid;
  int s=src[e], d=dst[e];
  float a[16];
  #pragma unroll
  for(int h=0;h<16;h++)
    a[h]=ws[F_EF+(size_t)e*16+h]+ws[F_PROJ+(size_t)s*16+h]+ws[F_PROJ+(size_t)d*16+h];
  int lane=tid&63;
  for(int o=0;o<64;o++){
    float z=0;
    #pragma unroll
    for(int h=0;h<16;h++) z+=w1s[o*16+h]*a[h];
    ws[F_Z1EC+(size_t)e*64+o]=z;
    float rs=waveSum(z), rq=waveSum(z*z);
    if(lane==0){ atomicAdd(&ws[SO_G1+o],rs); atomicAdd(&ws[SO_G1Q+o],rq); }
  }
}

// ---------------- edgeconv layer2 -> z2 [E,16] (in F_FCB) + stats ----------------
__global__ __launch_bounds__(256) void k_ec2(const float* __restrict__ ecW2, float* __restrict__ ws){
  __shared__ float w2s[1024];
  __shared__ float mi[64][2];
  int tid=threadIdx.x;
  for(int i=tid;i<1024;i+=256) w2s[i]=ecW2[i];
  if(tid<64){
    float m=ws[SO_G1+tid]*(1.0f/4096.0f);
    float v=ws[SO_G1Q+tid]*(1.0f/4096.0f)-m*m; if(v<0)v=0;
    mi[tid][0]=m; mi[tid][1]=rsqrtf(v+EPSB);
  }
  __syncthreads();
  int e=blockIdx.x*256+tid;
  float acc[16];
  #pragma unroll
  for(int k=0;k<16;k++) acc[k]=0;
  for(int o=0;o<64;o++){
    float z=ws[F_Z1EC+(size_t)e*64+o];
    float h=(z-mi[o][0])*mi[o][1];
    h=h>0?h:0;
    #pragma unroll
    for(int k=0;k<16;k++) acc[k]+=w2s[k*64+o]*h;
  }
  float s[16], q[16];
  #pragma unroll
  for(int k=0;k<16;k++){
    ws[F_FCB+(size_t)e*16+k]=acc[k];
    s[k]=acc[k]; q[k]=acc[k]*acc[k];
  }
  red32_atomic(ws, SO_G2, SO_G2Q, s, q);
}

// ---------------- edge_feature fill [4,1025,16] ----------------
__global__ __launch_bounds__(256) void k_ef2(float* __restrict__ ws){
  int t=blockIdx.x*256+threadIdx.x;
  if(t>=4*1025*16) return;
  int h=t&15, r=t>>4;
  int b=r/1025, pos=r%1025;
  float v=0;
  if(pos<1024){
    int e=b*1024+pos;
    float z=ws[F_FCB+(size_t)e*16+h];
    float m=ws[SO_G2+h]*(1.0f/4096.0f);
    float va=ws[SO_G2Q+h]*(1.0f/4096.0f)-m*m; if(va<0)va=0;
    v=(z-m)*rsqrtf(va+EPSB);
    v=v>0?v:0;
  }
  ws[F_EDGEF+t]=v;
}

// ---------------- main per-pair kernel: interior output ----------------
__global__ __launch_bounds__(256) void k_pair(const float* __restrict__ ab,
    const int* __restrict__ sd, const float* __restrict__ ang, const float* __restrict__ cen,
    const int* __restrict__ ep, const float* __restrict__ sdemb, const float* __restrict__ edisw,
    const float* __restrict__ angW1, const float* __restrict__ angW2,
    const float* __restrict__ cenW1, const float* __restrict__ cenW2,
    const float* __restrict__ ws, float* __restrict__ out){
  __shared__ float wd[1280];
  __shared__ float w2a[256], w2c[256];
  __shared__ float Aa[16], Ac[16], m2a[16], i2a[16], m2c[16], i2c[16];
  __shared__ float muA, muC, varA, varC;
  int tid=threadIdx.x;
  for(int i=tid;i<1280;i+=256) wd[i]=edisw[i];
  w2a[tid]=angW2[tid]; w2c[tid]=cenW2[tid];
  if(tid==0){
    float s=ws[SO_ANGX], q=ws[SO_ANGX+1];
    float mu=s*(1.0f/262144.0f);
    float v=q*(1.0f/262144.0f)-mu*mu; if(v<0)v=0;
    muA=mu; varA=v;
    s=ws[SO_CENX]; q=ws[SO_CENX+1];
    mu=s*(1.0f/262144.0f);
    v=q*(1.0f/262144.0f)-mu*mu; if(v<0)v=0;
    muC=mu; varC=v;
  }
  __syncthreads();
  if(tid<16){
    float w=angW1[tid]; Aa[tid]=w/sqrtf(varA*w*w+EPSB);
    float m=ws[SO_ANG2+tid]*(1.0f/262144.0f);
    float v=ws[SO_ANG2Q+tid]*(1.0f/262144.0f)-m*m; if(v<0)v=0;
    m2a[tid]=m; i2a[tid]=rsqrtf(v+EPSB);
  } else if(tid<32){
    int h=tid-16;
    float w=cenW1[h]; Ac[h]=w/sqrtf(varC*w*w+EPSB);
    float m=ws[SO_CEN2+h]*(1.0f/262144.0f);
    float v=ws[SO_CEN2Q+h]*(1.0f/262144.0f)-m*m; if(v<0)v=0;
    m2c[h]=m; i2c[h]=rsqrtf(v+EPSB);
  }
  __syncthreads();
  int t=blockIdx.x*256+tid;            // b,i,j
  int b=t>>16, rem=t&65535, i=rem>>8, j=rem&255;
  int sdv=sd[t];
  float xa=ang[t], xc0=cen[t];
  float acc[16];
  const float* se=sdemb+(size_t)sdv*16;
  #pragma unroll
  for(int k=0;k<16;k++) acc[k]=se[k];
  { // angle MLP
    float xc=xa-muA;
    float h1[16];
    #pragma unroll
    for(int h=0;h<16;h++){ float v=xc*Aa[h]; h1[h]=v>0?v:0; }
    #pragma unroll
    for(int k=0;k<16;k++){
      float z=0;
      #pragma unroll
      for(int h=0;h<16;h++) z+=w2a[k*16+h]*h1[h];
      float r=(z-m2a[k])*i2a[k];
      acc[k]+= r>0?r:0;
    }
  }
  { // centroid MLP
    float xc=xc0-muC;
    float h1[16];
    #pragma unroll
    for(int h=0;h<16;h++){ float v=xc*Ac[h]; h1[h]=v>0?v:0; }
    #pragma unroll
    for(int k=0;k<16;k++){
      float z=0;
      #pragma unroll
      for(int h=0;h<16;h++) z+=w2c[k*16+h]*h1[h];
      float r=(z-m2c[k])*i2c[k];
      acc[k]+= r>0?r:0;
    }
  }
  { // multi-hop edge bias
    int sdm = sdv==0 ? 1 : sdv;
    if(sdm>1) sdm-=1;
    if(sdm>5) sdm=5;
    float inv=1.0f/((float)sdm+1e-6f);
    float eb[16];
    #pragma unroll
    for(int k=0;k<16;k++) eb[k]=0;
    const float* EF=ws+F_EDGEF+(size_t)b*1025*16;
    #pragma unroll
    for(int d=0;d<5;d++){
      int idx=ep[(size_t)t*5+d];
      const float* r=EF+(size_t)idx*16;
      float e16[16];
      #pragma unroll
      for(int k=0;k<16;k+=4){
        float4 v=*(const float4*)(r+k);
        e16[k]=v.x; e16[k+1]=v.y; e16[k+2]=v.z; e16[k+3]=v.w;
      }
      const float* wdd=wd+d*256;
      #pragma unroll
      for(int h=0;h<16;h++){
        float evv=e16[h];
        #pragma unroll
        for(int k=0;k<16;k++) eb[k]+=evv*wdd[h*16+k];
      }
    }
    #pragma unroll
    for(int k=0;k<16;k++) acc[k]+=eb[k]*inv;
  }
  float base2=2.0f*ab[(size_t)b*66049+(size_t)(i+1)*257+(j+1)];
  #pragma unroll
  for(int k=0;k<16;k++)
    out[(((size_t)b*16+k)*257+(i+1))*257+(j+1)]=acc[k]+base2;
}

// ---------------- borders: row 0 and col 0 ----------------
__global__ __launch_bounds__(256) void k_border(const float* __restrict__ ab,
    const float* __restrict__ virt, float* __restrict__ out){
  int t=blockIdx.x*256+threadIdx.x;
  if(t>=4*16*513) return;
  int idx=t%513, bh=t/513;
  int b=bh>>4, h=bh&15;
  float v=virt[h];
  if(idx<257){
    out[(((size_t)b*16+h)*257)*257+idx]=2.0f*ab[(size_t)b*66049+idx]+v;
  } else {
    int p=idx-256;   // 1..256
    out[(((size_t)b*16+h)*257+p)*257]=2.0f*ab[(size_t)b*66049+(size_t)p*257]+v;
  }
}

extern "C" void kernel_launch(void* const* d_in, const int* in_sizes, int n_in,
                              void* d_out, int out_size, void* d_ws, size_t ws_size,
                              hipStream_t stream) {
  const float* ab    =(const float*)d_in[0];
  const int*   sdist =(const int*)  d_in[1];
  const float* ang   =(const float*)d_in[2];
  const float* cen   =(const float*)d_in[3];
  const int*   ep    =(const int*)  d_in[4];
  const float* edata =(const float*)d_in[5];
  const float* etype =(const float*)d_in[6];
  const float* elen  =(const float*)d_in[7];
  const float* econv =(const float*)d_in[8];
  const int*   src   =(const int*)  d_in[10];
  const int*   dst   =(const int*)  d_in[11];
  const float* nf    =(const float*)d_in[12];
  const float* sdemb =(const float*)d_in[13];
  const float* virt  =(const float*)d_in[14];
  const float* angW1 =(const float*)d_in[15];
  const float* angW2 =(const float*)d_in[16];
  const float* cenW1 =(const float*)d_in[17];
  const float* cenW2 =(const float*)d_in[18];
  const float* etW1  =(const float*)d_in[19];
  const float* etW2  =(const float*)d_in[20];
  const float* elW1  =(const float*)d_in[21];
  const float* elW2  =(const float*)d_in[22];
  const float* evW1  =(const float*)d_in[23];
  const float* evW2  =(const float*)d_in[24];
  const float* c1w   =(const float*)d_in[25];
  const float* c2w   =(const float*)d_in[26];
  const float* c3w   =(const float*)d_in[27];
  const float* fcw   =(const float*)d_in[28];
  const float* edisw =(const float*)d_in[29];
  const float* ecWp  =(const float*)d_in[30];
  const float* ecW1  =(const float*)d_in[31];
  const float* ecW2  =(const float*)d_in[32];
  float* ws=(float*)d_ws;
  float* out=(float*)d_out;

  hipMemsetAsync(d_ws, 0, STATS_FLOATS*sizeof(float), stream);

  k_wprep<<<480,256,0,stream>>>(c2w,c3w,(ushort*)(ws+F_WT2),(ushort*)(ws+F_WT3));

  k_scalar_stats<<<256,256,0,stream>>>(ang,cen,ws);
  k_ac_l2stats<<<128,256,0,stream>>>(ang,angW1,angW2,ws,SO_ANGX,SO_ANG2,SO_ANG2Q);
  k_ac_l2stats<<<128,256,0,stream>>>(cen,cenW1,cenW2,ws,SO_CENX,SO_CEN2,SO_CEN2Q);

  k_conv1<<<256,256,0,stream>>>(edata,c1w,ws);
  k_convmf<64,128,8><<<512,256,0,stream>>>(ws+F_Y13,(const ushort*)(ws+F_WT2),ws+F_Y2,ws,
                                           SO_C1,SO_C1Q,SO_C2,SO_C2Q);
  k_convmf<128,256,4><<<1024,256,0,stream>>>(ws+F_Y2,(const ushort*)(ws+F_WT3),ws+F_Y13,ws,
                                             SO_C2,SO_C2Q,SO_C3,SO_C3Q);
  k_pool<<<4096,256,0,stream>>>(ws);
  k_fc<<<256,256,0,stream>>>(fcw,ws);

  k_small_l1<11><<<16,256,0,stream>>>(etype,etW1,ws,SO_ET1,SO_ET1Q);
  k_small_l1<1> <<<16,256,0,stream>>>(elen ,elW1,ws,SO_EL1,SO_EL1Q);
  k_small_l1<3> <<<16,256,0,stream>>>(econv,evW1,ws,SO_EV1,SO_EV1Q);
  k_small_l2<11><<<16,256,0,stream>>>(etype,etW1,etW2,ws,SO_ET1,SO_ET1Q,SO_ET2,SO_ET2Q);
  k_small_l2<1> <<<16,256,0,stream>>>(elen ,elW1,elW2,ws,SO_EL1,SO_EL1Q,SO_EL2,SO_EL2Q);
  k_small_l2<3> <<<16,256,0,stream>>>(econv,evW1,evW2,ws,SO_EV1,SO_EV1Q,SO_EV2,SO_EV2Q);

  k_ef<<<16,256,0,stream>>>(etype,etW1,etW2,elen,elW1,elW2,econv,evW1,evW2,ws);
  k_proj<<<64,256,0,stream>>>(nf,ecWp,ws);
  k_agg<<<16,256,0,stream>>>(src,dst,ecW1,ws);
  k_ec2<<<16,256,0,stream>>>(ecW2,ws);
  k_ef2<<<257,256,0,stream>>>(ws);

  k_pair<<<1024,256,0,stream>>>(ab,sdist,ang,cen,ep,sdemb,edisw,angW1,angW2,cenW1,cenW2,ws,out);
  k_border<<<129,256,0,stream>>>(ab,virt,out);
}